// Round 9
// baseline (815.046 us; speedup 1.0000x reference)
//
#include <hip/hip_runtime.h>
#include <hip/hip_bf16.h>

#define VOCAB 50000
#define DD 256
#define NCLS 10
#define BB 64
#define SS 512
#define HH 512
#define K3D 768

typedef __attribute__((ext_vector_type(8))) short bf16x8;
typedef __attribute__((ext_vector_type(8))) unsigned short ush8;
typedef __attribute__((ext_vector_type(4))) float f32x4;

static __device__ __forceinline__ unsigned short f2bf(float f) {
    __hip_bfloat16 h = __float2bfloat16(f);
    return *reinterpret_cast<unsigned short*>(&h);
}

// ---------------------------------------------------------------------------
// Kernel P: prep — convert conv_w, build Wscat (bf16 concat Wsl|Wsr), biascat.
// ---------------------------------------------------------------------------
__global__ __launch_bounds__(256) void prep_kernel(
    const float* __restrict__ conv_w,
    const float* __restrict__ Wsl, const float* __restrict__ Wsr,
    const float* __restrict__ bsl, const float* __restrict__ bl,
    const float* __restrict__ bsr, const float* __restrict__ br,
    unsigned short* __restrict__ convwb,
    unsigned short* __restrict__ wscat,
    float* __restrict__ biascat)
{
    const int bid = blockIdx.x;
    if (bid < 192) {
        const int g = bid * 256 + threadIdx.x;
        const float* src = conv_w + (size_t)g * 8;
        const float4 v0 = *(const float4*)(src);
        const float4 v1 = *(const float4*)(src + 4);
        ush8 o;
        o[0]=f2bf(v0.x); o[1]=f2bf(v0.y); o[2]=f2bf(v0.z); o[3]=f2bf(v0.w);
        o[4]=f2bf(v1.x); o[5]=f2bf(v1.y); o[6]=f2bf(v1.z); o[7]=f2bf(v1.w);
        *(ush8*)(convwb + (size_t)g * 8) = o;
    } else if (bid < 256) {
        const int g = (bid - 192) * 256 + threadIdx.x;
        const int row = g >> 5, d0 = (g & 31) * 8;
        const float* src = (row < 256 ? Wsl + (size_t)row * DD
                                      : Wsr + (size_t)(row - 256) * DD) + d0;
        const float4 v0 = *(const float4*)(src);
        const float4 v1 = *(const float4*)(src + 4);
        ush8 o;
        o[0]=f2bf(v0.x); o[1]=f2bf(v0.y); o[2]=f2bf(v0.z); o[3]=f2bf(v0.w);
        o[4]=f2bf(v1.x); o[5]=f2bf(v1.y); o[6]=f2bf(v1.z); o[7]=f2bf(v1.w);
        *(ush8*)(wscat + (size_t)g * 8) = o;
    } else {
        for (int i = threadIdx.x; i < 512; i += 256)
            biascat[i] = (i < 256) ? (bsl[i] + bl[i]) : (bsr[i - 256] + br[i - 256]);
    }
}

// ---------------------------------------------------------------------------
// Kernel 0: gather embedding rows -> bf16 e2[s*64+b][d]
// ---------------------------------------------------------------------------
__global__ __launch_bounds__(256) void gather_e_kernel(
    const int* __restrict__ x, const float* __restrict__ embed_w,
    unsigned short* __restrict__ e2)
{
    const int g = blockIdx.x * 256 + threadIdx.x;
    const int bs = g >> 5;                         // b*S + s
    const int b = bs >> 9, s = bs & (SS - 1);
    const int d0 = (g & 31) * 8;
    const float* src = embed_w + (size_t)x[bs] * DD + d0;
    const float4 v0 = *(const float4*)(src);
    const float4 v1 = *(const float4*)(src + 4);
    ush8 o;
    o[0]=f2bf(v0.x); o[1]=f2bf(v0.y); o[2]=f2bf(v0.z); o[3]=f2bf(v0.w);
    o[4]=f2bf(v1.x); o[5]=f2bf(v1.y); o[6]=f2bf(v1.z); o[7]=f2bf(v1.w);
    *(ush8*)(e2 + ((size_t)s * BB + b) * DD + d0) = o;
}

// ---------------------------------------------------------------------------
// Kernel 1: pre-GEMM as bf16 MFMA. Output in the recurrence's pre2 slot
// layout (fp32), biases folded. grid = 1024 blocks, 256 threads.
// ---------------------------------------------------------------------------
#define PPAD 72

__global__ __launch_bounds__(256) void pre_mfma_kernel(
    const unsigned short* __restrict__ wscat,
    const unsigned short* __restrict__ e2,
    const float* __restrict__ biascat,
    float* __restrict__ pre2_l, float* __restrict__ pre2_r)
{
    __shared__ unsigned short Abuf[2][128][PPAD];
    __shared__ unsigned short Bbuf[2][128][PPAD];

    const int mi  = blockIdx.x & 3;
    const int sbi = blockIdx.x >> 2;
    const int tid = threadIdx.x;
    const int w = tid >> 6, lane = tid & 63;
    const int lr = lane & 15, g = lane >> 4;
    const int lk = g * 8;

    f32x4 acc[2][8];
#pragma unroll
    for (int mt = 0; mt < 2; ++mt)
#pragma unroll
        for (int nt = 0; nt < 8; ++nt) acc[mt][nt] = (f32x4)(0.f);

    const int strow = tid >> 3;
    const int skc   = (tid & 7) * 8;

    auto stage = [&](int ks, int buf) {
        const int k0 = ks * 64;
#pragma unroll
        for (int j = 0; j < 4; ++j) {
            const int row = strow + 32 * j;
            *(bf16x8*)&Abuf[buf][row][skc] =
                *(const bf16x8*)(wscat + (size_t)(mi * 128 + row) * DD + k0 + skc);
            *(bf16x8*)&Bbuf[buf][row][skc] =
                *(const bf16x8*)(e2 + (size_t)(sbi * 128 + row) * DD + k0 + skc);
        }
    };

    stage(0, 0);
    int cur = 0;
    for (int ks = 0; ks < 4; ++ks) {
        __syncthreads();
        if (ks + 1 < 4) stage(ks + 1, cur ^ 1);
#pragma unroll
        for (int k2 = 0; k2 < 2; ++k2) {
            const int kk = k2 * 32 + lk;
            const bf16x8 a0 = *(const bf16x8*)&Abuf[cur][w * 32 + lr][kk];
            const bf16x8 a1 = *(const bf16x8*)&Abuf[cur][w * 32 + 16 + lr][kk];
#pragma unroll
            for (int nt = 0; nt < 8; ++nt) {
                const bf16x8 bv = *(const bf16x8*)&Bbuf[cur][nt * 16 + lr][kk];
                acc[0][nt] = __builtin_amdgcn_mfma_f32_16x16x32_bf16(a0, bv, acc[0][nt], 0, 0, 0);
                acc[1][nt] = __builtin_amdgcn_mfma_f32_16x16x32_bf16(a1, bv, acc[1][nt], 0, 0, 0);
            }
        }
        cur ^= 1;
    }

#pragma unroll
    for (int mt = 0; mt < 2; ++mt) {
        const int eg = mi * 128 + w * 32 + mt * 16 + g * 4;
        const float4 bia = *(const float4*)(biascat + eg);
        float* dstb = (eg >= 256) ? pre2_r : pre2_l;
        const int e = eg & 255;
#pragma unroll
        for (int nt = 0; nt < 8; ++nt) {
            const int sb = sbi * 128 + nt * 16 + lr;
            const int s = sb >> 6, bgq = (sb >> 4) & 3, b_loc = sb & 15;
            float4 v;
            v.x = acc[mt][nt][0] + bia.x;
            v.y = acc[mt][nt][1] + bia.y;
            v.z = acc[mt][nt][2] + bia.z;
            v.w = acc[mt][nt][3] + bia.w;
            *(float4*)(dstb + ((size_t)s * 4 + bgq) * 4096 + (e >> 2) * 64 + b_loc * 4) = v;
        }
    }
}

// ---------------------------------------------------------------------------
// Kernel 2: MFMA recurrence. 8 blocks (dir*4 + bg), 256 thr (4 waves).
// NO per-step barrier: per-quarter step-stamped LDS flags.
//   wflag[q] = k+1  : quarter q of state-for-step-(k+1) is in cbf[(k+1)&1]
//   rflag[q] = k+1  : wave q finished READING its step-k sfrag
// Wave wl writes quarter wl; rotation makes it read its OWN quarter first,
// so its first 8 MFMAs need no cross-wave wait; neighbor quarters are needed
// progressively later, when (steady-state, self-staggered) they're ready.
// ---------------------------------------------------------------------------
#define CSWZ(row, off) ((off) ^ (((row) & 15) << 4))

__global__ __launch_bounds__(256, 1) void recur_mfma_kernel(
    const float* __restrict__ Wl, const float* __restrict__ Wr,
    const float* __restrict__ cl0, const float* __restrict__ cr0,
    const float* __restrict__ pre2_l, const float* __restrict__ pre2_r,
    unsigned short* __restrict__ outl, unsigned short* __restrict__ outr)
{
    __shared__ unsigned short cbf[2][16 * 256];  // [buf][b][e] swizzled rows
    __shared__ unsigned wflag[4];
    __shared__ unsigned rflag[4];

    const int dir = blockIdx.x >> 2;
    const int bg  = blockIdx.x & 3;
    const int b0  = bg * 16;
    const int tid  = threadIdx.x;
    const int wl   = tid >> 6;
    const int lane = tid & 63;
    const int col  = lane & 15;   // batch row
    const int g    = lane >> 4;

    const float* W   = dir ? Wr : Wl;
    const float* c0  = dir ? cr0 : cl0;
    const float* pre = dir ? pre2_r : pre2_l;
    unsigned short* out = dir ? outr : outl;

    // stationary W as A-side fragments, PRE-ROTATED by 2*wl k-tiles:
    // wfrag[mt][i] holds k-tile kt=(i+2*wl)&7; m=e = wl*64+mt*16+col.
    bf16x8 wfrag[4][8];
#pragma unroll
    for (int mt = 0; mt < 4; ++mt)
#pragma unroll
        for (int i = 0; i < 8; ++i) {
            const int kt = (i + 2 * wl) & 7;
            const float* src = W + (size_t)(wl * 64 + mt * 16 + col) * DD
                                 + kt * 32 + g * 8;
            const float4 lo = *(const float4*)(src);
            const float4 hi = *(const float4*)(src + 4);
            ush8 p;
            p[0]=f2bf(lo.x); p[1]=f2bf(lo.y); p[2]=f2bf(lo.z); p[3]=f2bf(lo.w);
            p[4]=f2bf(hi.x); p[5]=f2bf(hi.y); p[6]=f2bf(hi.z); p[7]=f2bf(hi.w);
            wfrag[mt][i] = *(bf16x8*)&p;
        }

    // rotated sfrag byte-offsets (per-lane, hoisted; static reg indices)
    int soff[8];
#pragma unroll
    for (int i = 0; i < 8; ++i) {
        const int kt = (i + 2 * wl) & 7;
        soff[i] = CSWZ(col, kt * 64 + g * 16);
    }

    if (tid < 4) { wflag[tid] = 0u; rflag[tid] = 0u; }

    // init: cbf[0] = bf16(c0), out[t0] = bf16(c0)
    {
        const int blc = tid >> 4;
        const int ch  = tid & 15;
        const float* src = c0 + (size_t)(b0 + blc) * DD + ch * 16;
        const float4 v0 = *(const float4*)(src);
        const float4 v1 = *(const float4*)(src + 4);
        const float4 v2 = *(const float4*)(src + 8);
        const float4 v3 = *(const float4*)(src + 12);
        ush8 p0, p1;
        p0[0]=f2bf(v0.x); p0[1]=f2bf(v0.y); p0[2]=f2bf(v0.z); p0[3]=f2bf(v0.w);
        p0[4]=f2bf(v1.x); p0[5]=f2bf(v1.y); p0[6]=f2bf(v1.z); p0[7]=f2bf(v1.w);
        p1[0]=f2bf(v2.x); p1[1]=f2bf(v2.y); p1[2]=f2bf(v2.z); p1[3]=f2bf(v2.w);
        p1[4]=f2bf(v3.x); p1[5]=f2bf(v3.y); p1[6]=f2bf(v3.z); p1[7]=f2bf(v3.w);
        char* rowp = (char*)cbf[0] + blc * 512;
        *(ush8*)(rowp + CSWZ(blc, ch * 32))      = p0;
        *(ush8*)(rowp + CSWZ(blc, ch * 32 + 16)) = p1;
        const int t0 = dir ? 511 : 0;
        ush8* dst = (ush8*)(out + ((size_t)t0 * BB + b0 + blc) * DD + ch * 16);
        dst[0] = p0; dst[1] = p1;
    }

    // pre: strength-reduced pointer walk.
    const int lpre = (wl * 16 + g) * 64 + col * 4;
    const ptrdiff_t pstep = dir ? -(ptrdiff_t)16384 : (ptrdiff_t)16384;
    const float* p0 = pre + ((size_t)(dir ? 511 : 0) * 4 + bg) * 4096 + lpre;

    float4 pA0 = *(const float4*)(p0);
    float4 pA1 = *(const float4*)(p0 + 256);
    float4 pA2 = *(const float4*)(p0 + 512);
    float4 pA3 = *(const float4*)(p0 + 768);
    const float* p1p = p0 + pstep;
    float4 pB0 = *(const float4*)(p1p);
    float4 pB1 = *(const float4*)(p1p + 256);
    float4 pB2 = *(const float4*)(p1p + 512);
    float4 pB3 = *(const float4*)(p1p + 768);
    const float* pfetch = p0 + 2 * pstep;

    unsigned short* oplane = out + (size_t)(dir ? 510 : 1) * BB * DD
                                 + (b0 + col) * DD + wl * 64 + g * 4;
    const ptrdiff_t ostep = (dir ? -(ptrdiff_t)1 : (ptrdiff_t)1) * (BB * DD);

    __syncthreads();   // the ONLY barrier: init state + flags visible

    int cur = 0;
#pragma unroll 2
    for (int k = 0; k < SS - 1; ++k) {
        const unsigned uk = (unsigned)k;
        const char* rowp = (const char*)cbf[cur] + col * 512;

        // issue pre loads for step k+2 (fire early, stay in flight)
        const float4 pN0 = *(const float4*)(pfetch);
        const float4 pN1 = *(const float4*)(pfetch + 256);
        const float4 pN2 = *(const float4*)(pfetch + 512);
        const float4 pN3 = *(const float4*)(pfetch + 768);
        if (k < SS - 4) pfetch += pstep;

        f32x4 a0 = (f32x4)(0.f), a1 = (f32x4)(0.f);
        f32x4 a2 = (f32x4)(0.f), a3 = (f32x4)(0.f);
        bf16x8 sfrag[8];

        // 4 quarter-groups: spin (skip own) -> 2 reads -> 8 MFMAs
#pragma unroll
        for (int jq = 0; jq < 4; ++jq) {
            if (jq > 0) {
                const int q = (wl + jq) & 3;
                volatile unsigned* f = &wflag[q];
                while (*f < uk) {}
                asm volatile("" ::: "memory");
            }
            const int i0 = 2 * jq;
            sfrag[i0]     = *(const bf16x8*)(rowp + soff[i0]);
            sfrag[i0 + 1] = *(const bf16x8*)(rowp + soff[i0 + 1]);
            if (jq == 3) {
                // all sfrag reads issued; once landed, publish read-done
                asm volatile("s_waitcnt lgkmcnt(0)" ::: "memory");
                if (lane == 0) *(volatile unsigned*)&rflag[wl] = uk + 1u;
            }
            __builtin_amdgcn_s_setprio(1);
#pragma unroll
            for (int ii = i0; ii < i0 + 2; ++ii) {
                a0 = __builtin_amdgcn_mfma_f32_16x16x32_bf16(wfrag[0][ii], sfrag[ii], a0, 0, 0, 0);
                a1 = __builtin_amdgcn_mfma_f32_16x16x32_bf16(wfrag[1][ii], sfrag[ii], a1, 0, 0, 0);
                a2 = __builtin_amdgcn_mfma_f32_16x16x32_bf16(wfrag[2][ii], sfrag[ii], a2, 0, 0, 0);
                a3 = __builtin_amdgcn_mfma_f32_16x16x32_bf16(wfrag[3][ii], sfrag[ii], a3, 0, 0, 0);
            }
            __builtin_amdgcn_s_setprio(0);
        }

        // WAR guard: everyone must have finished READING cbf[cur^1] (their
        // step k-1 source) before we overwrite it. rflag[q] >= k means q's
        // step-(k-1) reads are done.
        {
            volatile unsigned* rf = rflag;
            while (rf[0] < uk || rf[1] < uk || rf[2] < uk || rf[3] < uk) {}
            asm volatile("" ::: "memory");
        }

        // epilogue: relu(acc+pre) -> LDS next-state + direct global out
        char* nbuf = (char*)cbf[cur ^ 1] + col * 512;
        auto epi = [&](int mt, const float4 pv, const f32x4 a) {
            const float v0 = fmaxf(a[0] + pv.x, 0.f);
            const float v1 = fmaxf(a[1] + pv.y, 0.f);
            const float v2 = fmaxf(a[2] + pv.z, 0.f);
            const float v3 = fmaxf(a[3] + pv.w, 0.f);
            uint2 uu;
            uu.x = (unsigned)f2bf(v0) | ((unsigned)f2bf(v1) << 16);
            uu.y = (unsigned)f2bf(v2) | ((unsigned)f2bf(v3) << 16);
            const int eoff = (wl * 64 + mt * 16 + g * 4) * 2;
            *(uint2*)(nbuf + CSWZ(col, eoff)) = uu;
            *(uint2*)(oplane + mt * 16) = uu;
        };
        epi(0, pA0, a0);
        epi(1, pA1, a1);
        epi(2, pA2, a2);
        epi(3, pA3, a3);

        // publish: data writes drained, then step-stamp our quarter
        asm volatile("s_waitcnt lgkmcnt(0)" ::: "memory");
        if (lane == 0) *(volatile unsigned*)&wflag[wl] = uk + 1u;

        pA0 = pB0; pA1 = pB1; pA2 = pB2; pA3 = pB3;
        pB0 = pN0; pB1 = pN1; pB2 = pN2; pB3 = pN3;
        oplane += ostep;
        cur ^= 1;
    }
}

// ---------------------------------------------------------------------------
// Kernel 3: conv(1x3D) + relu + maxpool, bf16 MFMA.
// left/right in [t][b][e] layout (same indexing form as e2).
// ---------------------------------------------------------------------------
#define KSTEP 64
#define NK 12
#define NST 4
#define APAD 72

__global__ __launch_bounds__(256) void conv_pool_kernel(
    const unsigned short* __restrict__ leftb,
    const unsigned short* __restrict__ e2,
    const unsigned short* __restrict__ rightb,
    const unsigned short* __restrict__ convwb,
    const float* __restrict__ conv_b,
    float* __restrict__ pooled)
{
    __shared__ unsigned short Abuf[2][128][APAD];
    __shared__ unsigned short Bbuf[2][128][APAD];
    __shared__ float red[4][128];

    const int b   = blockIdx.x >> 2;
    const int h0  = (blockIdx.x & 3) * 128;
    const int tid = threadIdx.x;
    const int wid = tid >> 6;
    const int lane = tid & 63;
    const int lr  = lane & 15;
    const int lk  = (lane >> 4) * 8;

    f32x4 acc[2][8];
    float pmax[8];
#pragma unroll
    for (int ht = 0; ht < 8; ++ht) {
        pmax[ht] = -INFINITY;
        acc[0][ht] = (f32x4)(0.f);
        acc[1][ht] = (f32x4)(0.f);
    }

    const int strow = tid >> 3;
    const int skc   = (tid & 7) * 8;

    auto stage = [&](int it, int buf) {
        const int stile = it / NK, kstep = it % NK;
        const int k0 = kstep * KSTEP;
        const int s0 = stile * 128;
        const unsigned short* asrc;
        int koff;
        if (k0 < DD)          { asrc = leftb;  koff = k0; }
        else if (k0 < 2 * DD) { asrc = e2;     koff = k0 - DD; }
        else                  { asrc = rightb; koff = k0 - 2 * DD; }
#pragma unroll
        for (int j = 0; j < 4; ++j) {
            const int row = strow + 32 * j;
            const int ss = s0 + row;
            *(bf16x8*)&Abuf[buf][row][skc] =
                *(const bf16x8*)(asrc + ((size_t)ss * BB + b) * DD + koff + skc);
            *(bf16x8*)&Bbuf[buf][row][skc] =
                *(const bf16x8*)(convwb + (size_t)(h0 + row) * K3D + k0 + skc);
        }
    };

    stage(0, 0);
    int cur = 0;
    for (int it = 0; it < NST * NK; ++it) {
        __syncthreads();
        if (it + 1 < NST * NK) stage(it + 1, cur ^ 1);

        const int wrow0 = wid * 32;
#pragma unroll
        for (int ks = 0; ks < 2; ++ks) {
            const int kk = ks * 32 + lk;
            const bf16x8 a0 = *(const bf16x8*)&Abuf[cur][wrow0 + lr][kk];
            const bf16x8 a1 = *(const bf16x8*)&Abuf[cur][wrow0 + 16 + lr][kk];
#pragma unroll
            for (int ht = 0; ht < 8; ++ht) {
                const bf16x8 bv = *(const bf16x8*)&Bbuf[cur][ht * 16 + lr][kk];
                acc[0][ht] = __builtin_amdgcn_mfma_f32_16x16x32_bf16(a0, bv, acc[0][ht], 0, 0, 0);
                acc[1][ht] = __builtin_amdgcn_mfma_f32_16x16x32_bf16(a1, bv, acc[1][ht], 0, 0, 0);
            }
        }
        if ((it % NK) == NK - 1) {
#pragma unroll
            for (int st = 0; st < 2; ++st)
#pragma unroll
                for (int ht = 0; ht < 8; ++ht) {
#pragma unroll
                    for (int r = 0; r < 4; ++r)
                        pmax[ht] = fmaxf(pmax[ht], acc[st][ht][r]);
                    acc[st][ht] = (f32x4)(0.f);
                }
        }
        cur ^= 1;
    }

#pragma unroll
    for (int ht = 0; ht < 8; ++ht) {
        float m = pmax[ht];
        m = fmaxf(m, __shfl_xor(m, 16));
        m = fmaxf(m, __shfl_xor(m, 32));
        if (lane < 16) red[wid][ht * 16 + lane] = m;
    }
    __syncthreads();
    if (tid < 128) {
        const float m = fmaxf(fmaxf(red[0][tid], red[1][tid]),
                              fmaxf(red[2][tid], red[3][tid]));
        pooled[(size_t)b * HH + h0 + tid] = fmaxf(m + conv_b[h0 + tid], 0.f);
    }
}

// ---------------------------------------------------------------------------
// Kernel 4: final FC (unchanged).
// ---------------------------------------------------------------------------
__global__ void fc_kernel(const float* __restrict__ pooled,
                          const float* __restrict__ fc_w,
                          const float* __restrict__ fc_b,
                          float* __restrict__ out)
{
    const int t = threadIdx.x;
    if (t >= BB * NCLS) return;
    const int b = t / NCLS, c = t % NCLS;
    float acc = fc_b[c];
    for (int h = 0; h < HH; ++h)
        acc += pooled[(size_t)b * HH + h] * fc_w[(size_t)c * HH + h];
    out[b * NCLS + c] = acc;
}

// ---------------------------------------------------------------------------
extern "C" void kernel_launch(void* const* d_in, const int* in_sizes, int n_in,
                              void* d_out, int out_size, void* d_ws, size_t ws_size,
                              hipStream_t stream)
{
    const int*   x       = (const int*)  d_in[0];
    const float* embed_w = (const float*)d_in[1];
    const float* Wl      = (const float*)d_in[2];
    const float* bl      = (const float*)d_in[3];
    const float* Wsl     = (const float*)d_in[4];
    const float* bsl     = (const float*)d_in[5];
    const float* Wr      = (const float*)d_in[6];
    const float* br      = (const float*)d_in[7];
    const float* Wsr     = (const float*)d_in[8];
    const float* bsr     = (const float*)d_in[9];
    const float* conv_w  = (const float*)d_in[10];
    const float* conv_b  = (const float*)d_in[11];
    const float* fc_w    = (const float*)d_in[12];
    const float* fc_b    = (const float*)d_in[13];
    const float* cl0     = (const float*)d_in[14];
    const float* cr0     = (const float*)d_in[15];
    float* out = (float*)d_out;

    char* ws = (char*)d_ws;
    const size_t SZf = (size_t)SS * BB * DD * sizeof(float);           // 33.55 MB
    const size_t SZh = (size_t)SS * BB * DD * sizeof(unsigned short);  // 16.78 MB
    float*          pre2_l = (float*)(ws);
    float*          pre2_r = (float*)(ws + SZf);
    unsigned short* leftb  = (unsigned short*)(ws + 2 * SZf);
    unsigned short* rightb = (unsigned short*)(ws + 2 * SZf + SZh);
    unsigned short* e2     = (unsigned short*)(ws + 2 * SZf + 2 * SZh);
    unsigned short* convwb = (unsigned short*)(ws + 2 * SZf + 3 * SZh);
    unsigned short* wscat  = (unsigned short*)(ws + 2 * SZf + 3 * SZh + (size_t)HH * K3D * 2);
    float*          biascat= (float*)(ws + 2 * SZf + 3 * SZh + (size_t)HH * K3D * 2 + (size_t)512 * DD * 2);
    float*          pooled = (float*)(ws + 2 * SZf + 3 * SZh + (size_t)HH * K3D * 2 + (size_t)512 * DD * 2 + 2048);

    prep_kernel<<<257, 256, 0, stream>>>(conv_w, Wsl, Wsr, bsl, bl, bsr, br,
                                         convwb, wscat, biascat);

    gather_e_kernel<<<(BB * SS * DD / 8) / 256, 256, 0, stream>>>(x, embed_w, e2);

    pre_mfma_kernel<<<1024, 256, 0, stream>>>(wscat, e2, biascat, pre2_l, pre2_r);

    recur_mfma_kernel<<<8, 256, 0, stream>>>(
        Wl, Wr, cl0, cr0, pre2_l, pre2_r, leftb, rightb);

    conv_pool_kernel<<<BB * (HH / 128), 256, 0, stream>>>(
        leftb, e2, rightb, convwb, conv_b, pooled);

    fc_kernel<<<1, BB * NCLS, 0, stream>>>(pooled, fc_w, fc_b, out);
}

// Round 10
// 472.086 us; speedup vs baseline: 1.7265x; 1.7265x over previous
//
#include <hip/hip_runtime.h>
#include <hip/hip_bf16.h>

#define VOCAB 50000
#define DD 256
#define NCLS 10
#define BB 64
#define SS 512
#define HH 512
#define K3D 768

typedef __attribute__((ext_vector_type(8))) short bf16x8;
typedef __attribute__((ext_vector_type(8))) unsigned short ush8;
typedef __attribute__((ext_vector_type(4))) float f32x4;

static __device__ __forceinline__ unsigned short f2bf(float f) {
    __hip_bfloat16 h = __float2bfloat16(f);
    return *reinterpret_cast<unsigned short*>(&h);
}

// ---------------------------------------------------------------------------
// Kernel P: prep — convert conv_w, build Wscat (bf16 concat Wsl|Wsr), biascat.
// ---------------------------------------------------------------------------
__global__ __launch_bounds__(256) void prep_kernel(
    const float* __restrict__ conv_w,
    const float* __restrict__ Wsl, const float* __restrict__ Wsr,
    const float* __restrict__ bsl, const float* __restrict__ bl,
    const float* __restrict__ bsr, const float* __restrict__ br,
    unsigned short* __restrict__ convwb,
    unsigned short* __restrict__ wscat,
    float* __restrict__ biascat)
{
    const int bid = blockIdx.x;
    if (bid < 192) {
        const int g = bid * 256 + threadIdx.x;
        const float* src = conv_w + (size_t)g * 8;
        const float4 v0 = *(const float4*)(src);
        const float4 v1 = *(const float4*)(src + 4);
        ush8 o;
        o[0]=f2bf(v0.x); o[1]=f2bf(v0.y); o[2]=f2bf(v0.z); o[3]=f2bf(v0.w);
        o[4]=f2bf(v1.x); o[5]=f2bf(v1.y); o[6]=f2bf(v1.z); o[7]=f2bf(v1.w);
        *(ush8*)(convwb + (size_t)g * 8) = o;
    } else if (bid < 256) {
        const int g = (bid - 192) * 256 + threadIdx.x;
        const int row = g >> 5, d0 = (g & 31) * 8;
        const float* src = (row < 256 ? Wsl + (size_t)row * DD
                                      : Wsr + (size_t)(row - 256) * DD) + d0;
        const float4 v0 = *(const float4*)(src);
        const float4 v1 = *(const float4*)(src + 4);
        ush8 o;
        o[0]=f2bf(v0.x); o[1]=f2bf(v0.y); o[2]=f2bf(v0.z); o[3]=f2bf(v0.w);
        o[4]=f2bf(v1.x); o[5]=f2bf(v1.y); o[6]=f2bf(v1.z); o[7]=f2bf(v1.w);
        *(ush8*)(wscat + (size_t)g * 8) = o;
    } else {
        for (int i = threadIdx.x; i < 512; i += 256)
            biascat[i] = (i < 256) ? (bsl[i] + bl[i]) : (bsr[i - 256] + br[i - 256]);
    }
}

// ---------------------------------------------------------------------------
// Kernel 0: gather embedding rows -> bf16 e2[s*64+b][d]
// ---------------------------------------------------------------------------
__global__ __launch_bounds__(256) void gather_e_kernel(
    const int* __restrict__ x, const float* __restrict__ embed_w,
    unsigned short* __restrict__ e2)
{
    const int g = blockIdx.x * 256 + threadIdx.x;
    const int bs = g >> 5;                         // b*S + s
    const int b = bs >> 9, s = bs & (SS - 1);
    const int d0 = (g & 31) * 8;
    const float* src = embed_w + (size_t)x[bs] * DD + d0;
    const float4 v0 = *(const float4*)(src);
    const float4 v1 = *(const float4*)(src + 4);
    ush8 o;
    o[0]=f2bf(v0.x); o[1]=f2bf(v0.y); o[2]=f2bf(v0.z); o[3]=f2bf(v0.w);
    o[4]=f2bf(v1.x); o[5]=f2bf(v1.y); o[6]=f2bf(v1.z); o[7]=f2bf(v1.w);
    *(ush8*)(e2 + ((size_t)s * BB + b) * DD + d0) = o;
}

// ---------------------------------------------------------------------------
// Kernel 1: pre-GEMM as bf16 MFMA. Output in the recurrence's pre2 slot
// layout (fp32), biases folded. grid = 1024 blocks, 256 threads.
// ---------------------------------------------------------------------------
#define PPAD 72

__global__ __launch_bounds__(256) void pre_mfma_kernel(
    const unsigned short* __restrict__ wscat,
    const unsigned short* __restrict__ e2,
    const float* __restrict__ biascat,
    float* __restrict__ pre2_l, float* __restrict__ pre2_r)
{
    __shared__ unsigned short Abuf[2][128][PPAD];
    __shared__ unsigned short Bbuf[2][128][PPAD];

    const int mi  = blockIdx.x & 3;
    const int sbi = blockIdx.x >> 2;
    const int tid = threadIdx.x;
    const int w = tid >> 6, lane = tid & 63;
    const int lr = lane & 15, g = lane >> 4;
    const int lk = g * 8;

    f32x4 acc[2][8];
#pragma unroll
    for (int mt = 0; mt < 2; ++mt)
#pragma unroll
        for (int nt = 0; nt < 8; ++nt) acc[mt][nt] = (f32x4)(0.f);

    const int strow = tid >> 3;
    const int skc   = (tid & 7) * 8;

    auto stage = [&](int ks, int buf) {
        const int k0 = ks * 64;
#pragma unroll
        for (int j = 0; j < 4; ++j) {
            const int row = strow + 32 * j;
            *(bf16x8*)&Abuf[buf][row][skc] =
                *(const bf16x8*)(wscat + (size_t)(mi * 128 + row) * DD + k0 + skc);
            *(bf16x8*)&Bbuf[buf][row][skc] =
                *(const bf16x8*)(e2 + (size_t)(sbi * 128 + row) * DD + k0 + skc);
        }
    };

    stage(0, 0);
    int cur = 0;
    for (int ks = 0; ks < 4; ++ks) {
        __syncthreads();
        if (ks + 1 < 4) stage(ks + 1, cur ^ 1);
#pragma unroll
        for (int k2 = 0; k2 < 2; ++k2) {
            const int kk = k2 * 32 + lk;
            const bf16x8 a0 = *(const bf16x8*)&Abuf[cur][w * 32 + lr][kk];
            const bf16x8 a1 = *(const bf16x8*)&Abuf[cur][w * 32 + 16 + lr][kk];
#pragma unroll
            for (int nt = 0; nt < 8; ++nt) {
                const bf16x8 bv = *(const bf16x8*)&Bbuf[cur][nt * 16 + lr][kk];
                acc[0][nt] = __builtin_amdgcn_mfma_f32_16x16x32_bf16(a0, bv, acc[0][nt], 0, 0, 0);
                acc[1][nt] = __builtin_amdgcn_mfma_f32_16x16x32_bf16(a1, bv, acc[1][nt], 0, 0, 0);
            }
        }
        cur ^= 1;
    }

#pragma unroll
    for (int mt = 0; mt < 2; ++mt) {
        const int eg = mi * 128 + w * 32 + mt * 16 + g * 4;
        const float4 bia = *(const float4*)(biascat + eg);
        float* dstb = (eg >= 256) ? pre2_r : pre2_l;
        const int e = eg & 255;
#pragma unroll
        for (int nt = 0; nt < 8; ++nt) {
            const int sb = sbi * 128 + nt * 16 + lr;
            const int s = sb >> 6, bgq = (sb >> 4) & 3, b_loc = sb & 15;
            float4 v;
            v.x = acc[mt][nt][0] + bia.x;
            v.y = acc[mt][nt][1] + bia.y;
            v.z = acc[mt][nt][2] + bia.z;
            v.w = acc[mt][nt][3] + bia.w;
            *(float4*)(dstb + ((size_t)s * 4 + bgq) * 4096 + (e >> 2) * 64 + b_loc * 4) = v;
        }
    }
}

// ---------------------------------------------------------------------------
// Kernel 2: MFMA recurrence. 8 blocks (dir*4 + bg), 256 thr (4 waves).
// R8 structure (raw lgkm-barrier, rotation, dist-2 chains) with two VALU
// trims: (1) pre is fed as the MFMA C-input of each chain's first MFMA —
// no adds, no movs; (2) epilogue bf16 pack via v_cvt_pk_bf16_f32 (1 instr
// per 2 values instead of ~4-instr RNE sequence each).
// ---------------------------------------------------------------------------
#define CSWZ(row, off) ((off) ^ (((row) & 15) << 4))

__global__ __launch_bounds__(256, 1) void recur_mfma_kernel(
    const float* __restrict__ Wl, const float* __restrict__ Wr,
    const float* __restrict__ cl0, const float* __restrict__ cr0,
    const float* __restrict__ pre2_l, const float* __restrict__ pre2_r,
    unsigned short* __restrict__ outl, unsigned short* __restrict__ outr)
{
    __shared__ unsigned short cbf[2][16 * 256];  // [buf][b][e] swizzled rows

    const int dir = blockIdx.x >> 2;
    const int bg  = blockIdx.x & 3;
    const int b0  = bg * 16;
    const int tid  = threadIdx.x;
    const int wl   = tid >> 6;
    const int lane = tid & 63;
    const int col  = lane & 15;   // batch row
    const int g    = lane >> 4;

    const float* W   = dir ? Wr : Wl;
    const float* c0  = dir ? cr0 : cl0;
    const float* pre = dir ? pre2_r : pre2_l;
    unsigned short* out = dir ? outr : outl;

    // stationary W as A-side fragments, PRE-ROTATED by 2*wl k-tiles:
    // wfrag[mt][i] holds k-tile kt=(i+2*wl)&7; m=e = wl*64+mt*16+col.
    bf16x8 wfrag[4][8];
#pragma unroll
    for (int mt = 0; mt < 4; ++mt)
#pragma unroll
        for (int i = 0; i < 8; ++i) {
            const int kt = (i + 2 * wl) & 7;
            const float* src = W + (size_t)(wl * 64 + mt * 16 + col) * DD
                                 + kt * 32 + g * 8;
            const float4 lo = *(const float4*)(src);
            const float4 hi = *(const float4*)(src + 4);
            ush8 p;
            p[0]=f2bf(lo.x); p[1]=f2bf(lo.y); p[2]=f2bf(lo.z); p[3]=f2bf(lo.w);
            p[4]=f2bf(hi.x); p[5]=f2bf(hi.y); p[6]=f2bf(hi.z); p[7]=f2bf(hi.w);
            wfrag[mt][i] = *(bf16x8*)&p;
        }

    // rotated sfrag byte-offsets (per-lane, hoisted; static reg indices)
    int soff[8];
#pragma unroll
    for (int i = 0; i < 8; ++i) {
        const int kt = (i + 2 * wl) & 7;
        soff[i] = CSWZ(col, kt * 64 + g * 16);
    }

    // init: cbf[0] = bf16(c0), out[t0] = bf16(c0)
    {
        const int blc = tid >> 4;
        const int ch  = tid & 15;
        const float* src = c0 + (size_t)(b0 + blc) * DD + ch * 16;
        const float4 v0 = *(const float4*)(src);
        const float4 v1 = *(const float4*)(src + 4);
        const float4 v2 = *(const float4*)(src + 8);
        const float4 v3 = *(const float4*)(src + 12);
        ush8 p0, p1;
        p0[0]=f2bf(v0.x); p0[1]=f2bf(v0.y); p0[2]=f2bf(v0.z); p0[3]=f2bf(v0.w);
        p0[4]=f2bf(v1.x); p0[5]=f2bf(v1.y); p0[6]=f2bf(v1.z); p0[7]=f2bf(v1.w);
        p1[0]=f2bf(v2.x); p1[1]=f2bf(v2.y); p1[2]=f2bf(v2.z); p1[3]=f2bf(v2.w);
        p1[4]=f2bf(v3.x); p1[5]=f2bf(v3.y); p1[6]=f2bf(v3.z); p1[7]=f2bf(v3.w);
        char* rowp = (char*)cbf[0] + blc * 512;
        *(ush8*)(rowp + CSWZ(blc, ch * 32))      = p0;
        *(ush8*)(rowp + CSWZ(blc, ch * 32 + 16)) = p1;
        const int t0 = dir ? 511 : 0;
        ush8* dst = (ush8*)(out + ((size_t)t0 * BB + b0 + blc) * DD + ch * 16);
        dst[0] = p0; dst[1] = p1;
    }

    // pre: strength-reduced pointer walk. lane-invariant offset + step +-16K.
    const int lpre = (wl * 16 + g) * 64 + col * 4;
    const ptrdiff_t pstep = dir ? -(ptrdiff_t)16384 : (ptrdiff_t)16384;
    const float* p0 = pre + ((size_t)(dir ? 511 : 0) * 4 + bg) * 4096 + lpre;

    float4 pA0 = *(const float4*)(p0);
    float4 pA1 = *(const float4*)(p0 + 256);
    float4 pA2 = *(const float4*)(p0 + 512);
    float4 pA3 = *(const float4*)(p0 + 768);
    const float* p1p = p0 + pstep;
    float4 pB0 = *(const float4*)(p1p);
    float4 pB1 = *(const float4*)(p1p + 256);
    float4 pB2 = *(const float4*)(p1p + 512);
    float4 pB3 = *(const float4*)(p1p + 768);
    const float* pfetch = p0 + 2 * pstep;

    // out: strength-reduced pointer walk (per-lane base, +-BB*DD per step)
    unsigned short* oplane = out + (size_t)(dir ? 510 : 1) * BB * DD
                                 + (b0 + col) * DD + wl * 64 + g * 4;
    const ptrdiff_t ostep = (dir ? -(ptrdiff_t)1 : (ptrdiff_t)1) * (BB * DD);

    __syncthreads();

    int cur = 0;
#pragma unroll 2
    for (int k = 0; k < SS - 1; ++k) {
        // state B-fragments from cbf[cur], rotated read order (runtime addr OK)
        bf16x8 sfrag[8];
        {
            const char* rowp = (const char*)cbf[cur] + col * 512;
#pragma unroll
            for (int i = 0; i < 8; ++i)
                sfrag[i] = *(const bf16x8*)(rowp + soff[i]);
        }

        // issue pre loads for step k+2 (stay in flight across the barrier)
        const float4 pN0 = *(const float4*)(pfetch);
        const float4 pN1 = *(const float4*)(pfetch + 256);
        const float4 pN2 = *(const float4*)(pfetch + 512);
        const float4 pN3 = *(const float4*)(pfetch + 768);
        if (k < SS - 4) pfetch += pstep;

        char* nbuf = (char*)cbf[cur ^ 1] + col * 512;

        // per-mt epilogue: relu(acc) -> LDS next-state + direct global out.
        // (pre already inside acc via the MFMA C-input.)
        auto epi = [&](int mt, const f32x4 a) {
            const float v0 = fmaxf(a[0], 0.f);
            const float v1 = fmaxf(a[1], 0.f);
            const float v2 = fmaxf(a[2], 0.f);
            const float v3 = fmaxf(a[3], 0.f);
            uint2 uu;
            asm("v_cvt_pk_bf16_f32 %0, %1, %2" : "=v"(uu.x) : "v"(v0), "v"(v1));
            asm("v_cvt_pk_bf16_f32 %0, %1, %2" : "=v"(uu.y) : "v"(v2), "v"(v3));
            const int eoff = (wl * 64 + mt * 16 + g * 4) * 2;
            *(uint2*)(nbuf + CSWZ(col, eoff)) = uu;
            *(uint2*)(oplane + mt * 16) = uu;
        };

        // half-round 1: chains 0,1 interleaved; C-in of first MFMA = pre
        f32x4 a0 = *(const f32x4*)&pA0;
        f32x4 a1 = *(const f32x4*)&pA1;
        __builtin_amdgcn_s_setprio(1);
#pragma unroll
        for (int i = 0; i < 8; ++i) {
            a0 = __builtin_amdgcn_mfma_f32_16x16x32_bf16(wfrag[0][i], sfrag[i], a0, 0, 0, 0);
            a1 = __builtin_amdgcn_mfma_f32_16x16x32_bf16(wfrag[1][i], sfrag[i], a1, 0, 0, 0);
        }
        __builtin_amdgcn_s_setprio(0);
        epi(0, a0);
        epi(1, a1);

        // half-round 2: chains 2,3 (epi 0/1 hides under these)
        f32x4 a2 = *(const f32x4*)&pA2;
        f32x4 a3 = *(const f32x4*)&pA3;
        __builtin_amdgcn_s_setprio(1);
#pragma unroll
        for (int i = 0; i < 8; ++i) {
            a2 = __builtin_amdgcn_mfma_f32_16x16x32_bf16(wfrag[2][i], sfrag[i], a2, 0, 0, 0);
            a3 = __builtin_amdgcn_mfma_f32_16x16x32_bf16(wfrag[3][i], sfrag[i], a3, 0, 0, 0);
        }
        __builtin_amdgcn_s_setprio(0);
        epi(2, a2);
        epi(3, a3);

        pA0 = pB0; pA1 = pB1; pA2 = pB2; pA3 = pB3;
        pB0 = pN0; pB1 = pN1; pB2 = pN2; pB3 = pN3;
        oplane += ostep;

        // raw barrier: drain LDS ops only; global loads stay in flight
        asm volatile("s_waitcnt lgkmcnt(0)" ::: "memory");
        __builtin_amdgcn_s_barrier();
        asm volatile("" ::: "memory");
        cur ^= 1;
    }
}

// ---------------------------------------------------------------------------
// Kernel 3: conv(1x3D) + relu + maxpool, bf16 MFMA.
// left/right in [t][b][e] layout (same indexing form as e2).
// ---------------------------------------------------------------------------
#define KSTEP 64
#define NK 12
#define NST 4
#define APAD 72

__global__ __launch_bounds__(256) void conv_pool_kernel(
    const unsigned short* __restrict__ leftb,
    const unsigned short* __restrict__ e2,
    const unsigned short* __restrict__ rightb,
    const unsigned short* __restrict__ convwb,
    const float* __restrict__ conv_b,
    float* __restrict__ pooled)
{
    __shared__ unsigned short Abuf[2][128][APAD];
    __shared__ unsigned short Bbuf[2][128][APAD];
    __shared__ float red[4][128];

    const int b   = blockIdx.x >> 2;
    const int h0  = (blockIdx.x & 3) * 128;
    const int tid = threadIdx.x;
    const int wid = tid >> 6;
    const int lane = tid & 63;
    const int lr  = lane & 15;
    const int lk  = (lane >> 4) * 8;

    f32x4 acc[2][8];
    float pmax[8];
#pragma unroll
    for (int ht = 0; ht < 8; ++ht) {
        pmax[ht] = -INFINITY;
        acc[0][ht] = (f32x4)(0.f);
        acc[1][ht] = (f32x4)(0.f);
    }

    const int strow = tid >> 3;
    const int skc   = (tid & 7) * 8;

    auto stage = [&](int it, int buf) {
        const int stile = it / NK, kstep = it % NK;
        const int k0 = kstep * KSTEP;
        const int s0 = stile * 128;
        const unsigned short* asrc;
        int koff;
        if (k0 < DD)          { asrc = leftb;  koff = k0; }
        else if (k0 < 2 * DD) { asrc = e2;     koff = k0 - DD; }
        else                  { asrc = rightb; koff = k0 - 2 * DD; }
#pragma unroll
        for (int j = 0; j < 4; ++j) {
            const int row = strow + 32 * j;
            const int ss = s0 + row;
            *(bf16x8*)&Abuf[buf][row][skc] =
                *(const bf16x8*)(asrc + ((size_t)ss * BB + b) * DD + koff + skc);
            *(bf16x8*)&Bbuf[buf][row][skc] =
                *(const bf16x8*)(convwb + (size_t)(h0 + row) * K3D + k0 + skc);
        }
    };

    stage(0, 0);
    int cur = 0;
    for (int it = 0; it < NST * NK; ++it) {
        __syncthreads();
        if (it + 1 < NST * NK) stage(it + 1, cur ^ 1);

        const int wrow0 = wid * 32;
#pragma unroll
        for (int ks = 0; ks < 2; ++ks) {
            const int kk = ks * 32 + lk;
            const bf16x8 a0 = *(const bf16x8*)&Abuf[cur][wrow0 + lr][kk];
            const bf16x8 a1 = *(const bf16x8*)&Abuf[cur][wrow0 + 16 + lr][kk];
#pragma unroll
            for (int ht = 0; ht < 8; ++ht) {
                const bf16x8 bv = *(const bf16x8*)&Bbuf[cur][ht * 16 + lr][kk];
                acc[0][ht] = __builtin_amdgcn_mfma_f32_16x16x32_bf16(a0, bv, acc[0][ht], 0, 0, 0);
                acc[1][ht] = __builtin_amdgcn_mfma_f32_16x16x32_bf16(a1, bv, acc[1][ht], 0, 0, 0);
            }
        }
        if ((it % NK) == NK - 1) {
#pragma unroll
            for (int st = 0; st < 2; ++st)
#pragma unroll
                for (int ht = 0; ht < 8; ++ht) {
#pragma unroll
                    for (int r = 0; r < 4; ++r)
                        pmax[ht] = fmaxf(pmax[ht], acc[st][ht][r]);
                    acc[st][ht] = (f32x4)(0.f);
                }
        }
        cur ^= 1;
    }

#pragma unroll
    for (int ht = 0; ht < 8; ++ht) {
        float m = pmax[ht];
        m = fmaxf(m, __shfl_xor(m, 16));
        m = fmaxf(m, __shfl_xor(m, 32));
        if (lane < 16) red[wid][ht * 16 + lane] = m;
    }
    __syncthreads();
    if (tid < 128) {
        const float m = fmaxf(fmaxf(red[0][tid], red[1][tid]),
                              fmaxf(red[2][tid], red[3][tid]));
        pooled[(size_t)b * HH + h0 + tid] = fmaxf(m + conv_b[h0 + tid], 0.f);
    }
}

// ---------------------------------------------------------------------------
// Kernel 4: final FC (unchanged).
// ---------------------------------------------------------------------------
__global__ void fc_kernel(const float* __restrict__ pooled,
                          const float* __restrict__ fc_w,
                          const float* __restrict__ fc_b,
                          float* __restrict__ out)
{
    const int t = threadIdx.x;
    if (t >= BB * NCLS) return;
    const int b = t / NCLS, c = t % NCLS;
    float acc = fc_b[c];
    for (int h = 0; h < HH; ++h)
        acc += pooled[(size_t)b * HH + h] * fc_w[(size_t)c * HH + h];
    out[b * NCLS + c] = acc;
}

// ---------------------------------------------------------------------------
extern "C" void kernel_launch(void* const* d_in, const int* in_sizes, int n_in,
                              void* d_out, int out_size, void* d_ws, size_t ws_size,
                              hipStream_t stream)
{
    const int*   x       = (const int*)  d_in[0];
    const float* embed_w = (const float*)d_in[1];
    const float* Wl      = (const float*)d_in[2];
    const float* bl      = (const float*)d_in[3];
    const float* Wsl     = (const float*)d_in[4];
    const float* bsl     = (const float*)d_in[5];
    const float* Wr      = (const float*)d_in[6];
    const float* br      = (const float*)d_in[7];
    const float* Wsr     = (const float*)d_in[8];
    const float* bsr     = (const float*)d_in[9];
    const float* conv_w  = (const float*)d_in[10];
    const float* conv_b  = (const float*)d_in[11];
    const float* fc_w    = (const float*)d_in[12];
    const float* fc_b    = (const float*)d_in[13];
    const float* cl0     = (const float*)d_in[14];
    const float* cr0     = (const float*)d_in[15];
    float* out = (float*)d_out;

    char* ws = (char*)d_ws;
    const size_t SZf = (size_t)SS * BB * DD * sizeof(float);           // 33.55 MB
    const size_t SZh = (size_t)SS * BB * DD * sizeof(unsigned short);  // 16.78 MB
    float*          pre2_l = (float*)(ws);
    float*          pre2_r = (float*)(ws + SZf);
    unsigned short* leftb  = (unsigned short*)(ws + 2 * SZf);
    unsigned short* rightb = (unsigned short*)(ws + 2 * SZf + SZh);
    unsigned short* e2     = (unsigned short*)(ws + 2 * SZf + 2 * SZh);
    unsigned short* convwb = (unsigned short*)(ws + 2 * SZf + 3 * SZh);
    unsigned short* wscat  = (unsigned short*)(ws + 2 * SZf + 3 * SZh + (size_t)HH * K3D * 2);
    float*          biascat= (float*)(ws + 2 * SZf + 3 * SZh + (size_t)HH * K3D * 2 + (size_t)512 * DD * 2);
    float*          pooled = (float*)(ws + 2 * SZf + 3 * SZh + (size_t)HH * K3D * 2 + (size_t)512 * DD * 2 + 2048);

    prep_kernel<<<257, 256, 0, stream>>>(conv_w, Wsl, Wsr, bsl, bl, bsr, br,
                                         convwb, wscat, biascat);

    gather_e_kernel<<<(BB * SS * DD / 8) / 256, 256, 0, stream>>>(x, embed_w, e2);

    pre_mfma_kernel<<<1024, 256, 0, stream>>>(wscat, e2, biascat, pre2_l, pre2_r);

    recur_mfma_kernel<<<8, 256, 0, stream>>>(
        Wl, Wr, cl0, cr0, pre2_l, pre2_r, leftb, rightb);

    conv_pool_kernel<<<BB * (HH / 128), 256, 0, stream>>>(
        leftb, e2, rightb, convwb, conv_b, pooled);

    fc_kernel<<<1, BB * NCLS, 0, stream>>>(pooled, fc_w, fc_b, out);
}

// Round 11
// 447.007 us; speedup vs baseline: 1.8233x; 1.0561x over previous
//
#include <hip/hip_runtime.h>
#include <hip/hip_bf16.h>

#define VOCAB 50000
#define DD 256
#define NCLS 10
#define BB 64
#define SS 512
#define HH 512
#define K3D 768

typedef __attribute__((ext_vector_type(8))) short bf16x8;
typedef __attribute__((ext_vector_type(8))) unsigned short ush8;
typedef __attribute__((ext_vector_type(4))) float f32x4;

static __device__ __forceinline__ unsigned short f2bf(float f) {
    __hip_bfloat16 h = __float2bfloat16(f);
    return *reinterpret_cast<unsigned short*>(&h);
}

// ---------------------------------------------------------------------------
// Kernel P: prep + gather fused.
// bid<192: conv_w->bf16 | bid<256: wscat | bid==256: biascat | else gather e2
// ---------------------------------------------------------------------------
__global__ __launch_bounds__(256) void prep_gather_kernel(
    const float* __restrict__ conv_w,
    const float* __restrict__ Wsl, const float* __restrict__ Wsr,
    const float* __restrict__ bsl, const float* __restrict__ bl,
    const float* __restrict__ bsr, const float* __restrict__ br,
    const int* __restrict__ x, const float* __restrict__ embed_w,
    unsigned short* __restrict__ convwb,
    unsigned short* __restrict__ wscat,
    float* __restrict__ biascat,
    unsigned short* __restrict__ e2)
{
    const int bid = blockIdx.x;
    if (bid < 192) {
        const int g = bid * 256 + threadIdx.x;
        const float* src = conv_w + (size_t)g * 8;
        const float4 v0 = *(const float4*)(src);
        const float4 v1 = *(const float4*)(src + 4);
        ush8 o;
        o[0]=f2bf(v0.x); o[1]=f2bf(v0.y); o[2]=f2bf(v0.z); o[3]=f2bf(v0.w);
        o[4]=f2bf(v1.x); o[5]=f2bf(v1.y); o[6]=f2bf(v1.z); o[7]=f2bf(v1.w);
        *(ush8*)(convwb + (size_t)g * 8) = o;
    } else if (bid < 256) {
        const int g = (bid - 192) * 256 + threadIdx.x;
        const int row = g >> 5, d0 = (g & 31) * 8;
        const float* src = (row < 256 ? Wsl + (size_t)row * DD
                                      : Wsr + (size_t)(row - 256) * DD) + d0;
        const float4 v0 = *(const float4*)(src);
        const float4 v1 = *(const float4*)(src + 4);
        ush8 o;
        o[0]=f2bf(v0.x); o[1]=f2bf(v0.y); o[2]=f2bf(v0.z); o[3]=f2bf(v0.w);
        o[4]=f2bf(v1.x); o[5]=f2bf(v1.y); o[6]=f2bf(v1.z); o[7]=f2bf(v1.w);
        *(ush8*)(wscat + (size_t)g * 8) = o;
    } else if (bid == 256) {
        for (int i = threadIdx.x; i < 512; i += 256)
            biascat[i] = (i < 256) ? (bsl[i] + bl[i]) : (bsr[i - 256] + br[i - 256]);
    } else {
        const int g = (bid - 257) * 256 + threadIdx.x;
        const int bs = g >> 5;                         // b*S + s
        const int b = bs >> 9, s = bs & (SS - 1);
        const int d0 = (g & 31) * 8;
        const float* src = embed_w + (size_t)x[bs] * DD + d0;
        const float4 v0 = *(const float4*)(src);
        const float4 v1 = *(const float4*)(src + 4);
        ush8 o;
        o[0]=f2bf(v0.x); o[1]=f2bf(v0.y); o[2]=f2bf(v0.z); o[3]=f2bf(v0.w);
        o[4]=f2bf(v1.x); o[5]=f2bf(v1.y); o[6]=f2bf(v1.z); o[7]=f2bf(v1.w);
        *(ush8*)(e2 + ((size_t)s * BB + b) * DD + d0) = o;
    }
}

// ---------------------------------------------------------------------------
// Kernel 1: pre-GEMM as bf16 MFMA (unchanged).
// ---------------------------------------------------------------------------
#define PPAD 72

__global__ __launch_bounds__(256) void pre_mfma_kernel(
    const unsigned short* __restrict__ wscat,
    const unsigned short* __restrict__ e2,
    const float* __restrict__ biascat,
    float* __restrict__ pre2_l, float* __restrict__ pre2_r)
{
    __shared__ unsigned short Abuf[2][128][PPAD];
    __shared__ unsigned short Bbuf[2][128][PPAD];

    const int mi  = blockIdx.x & 3;
    const int sbi = blockIdx.x >> 2;
    const int tid = threadIdx.x;
    const int w = tid >> 6, lane = tid & 63;
    const int lr = lane & 15, g = lane >> 4;
    const int lk = g * 8;

    f32x4 acc[2][8];
#pragma unroll
    for (int mt = 0; mt < 2; ++mt)
#pragma unroll
        for (int nt = 0; nt < 8; ++nt) acc[mt][nt] = (f32x4)(0.f);

    const int strow = tid >> 3;
    const int skc   = (tid & 7) * 8;

    auto stage = [&](int ks, int buf) {
        const int k0 = ks * 64;
#pragma unroll
        for (int j = 0; j < 4; ++j) {
            const int row = strow + 32 * j;
            *(bf16x8*)&Abuf[buf][row][skc] =
                *(const bf16x8*)(wscat + (size_t)(mi * 128 + row) * DD + k0 + skc);
            *(bf16x8*)&Bbuf[buf][row][skc] =
                *(const bf16x8*)(e2 + (size_t)(sbi * 128 + row) * DD + k0 + skc);
        }
    };

    stage(0, 0);
    int cur = 0;
    for (int ks = 0; ks < 4; ++ks) {
        __syncthreads();
        if (ks + 1 < 4) stage(ks + 1, cur ^ 1);
#pragma unroll
        for (int k2 = 0; k2 < 2; ++k2) {
            const int kk = k2 * 32 + lk;
            const bf16x8 a0 = *(const bf16x8*)&Abuf[cur][w * 32 + lr][kk];
            const bf16x8 a1 = *(const bf16x8*)&Abuf[cur][w * 32 + 16 + lr][kk];
#pragma unroll
            for (int nt = 0; nt < 8; ++nt) {
                const bf16x8 bv = *(const bf16x8*)&Bbuf[cur][nt * 16 + lr][kk];
                acc[0][nt] = __builtin_amdgcn_mfma_f32_16x16x32_bf16(a0, bv, acc[0][nt], 0, 0, 0);
                acc[1][nt] = __builtin_amdgcn_mfma_f32_16x16x32_bf16(a1, bv, acc[1][nt], 0, 0, 0);
            }
        }
        cur ^= 1;
    }

#pragma unroll
    for (int mt = 0; mt < 2; ++mt) {
        const int eg = mi * 128 + w * 32 + mt * 16 + g * 4;
        const float4 bia = *(const float4*)(biascat + eg);
        float* dstb = (eg >= 256) ? pre2_r : pre2_l;
        const int e = eg & 255;
#pragma unroll
        for (int nt = 0; nt < 8; ++nt) {
            const int sb = sbi * 128 + nt * 16 + lr;
            const int s = sb >> 6, bgq = (sb >> 4) & 3, b_loc = sb & 15;
            float4 v;
            v.x = acc[mt][nt][0] + bia.x;
            v.y = acc[mt][nt][1] + bia.y;
            v.z = acc[mt][nt][2] + bia.z;
            v.w = acc[mt][nt][3] + bia.w;
            *(float4*)(dstb + ((size_t)s * 4 + bgq) * 4096 + (e >> 2) * 64 + b_loc * 4) = v;
        }
    }
}

// ---------------------------------------------------------------------------
// Kernel 2: FUSED recur (blocks 0..7, R10 structure untouched) + conv_e
// (blocks 8..135, 2 tiles each): h_e partials = e2 @ conv_w[:,256:512]^T,
// written to hpart (bf16) in conv_pool's fragment-slot layout. conv_e has no
// dependency on recur — it fills the 248 idle CUs during the recurrence.
// ---------------------------------------------------------------------------
#define CSWZ(row, off) ((off) ^ (((row) & 15) << 4))
#define APAD 72

__global__ __launch_bounds__(256, 1) void recur_conve_kernel(
    const float* __restrict__ Wl, const float* __restrict__ Wr,
    const float* __restrict__ cl0, const float* __restrict__ cr0,
    const float* __restrict__ pre2_l, const float* __restrict__ pre2_r,
    unsigned short* __restrict__ outl, unsigned short* __restrict__ outr,
    const unsigned short* __restrict__ e2,
    const unsigned short* __restrict__ convwb,
    unsigned short* __restrict__ hpart)
{
    __shared__ alignas(16) unsigned char smem[2 * 2 * 128 * APAD * 2];  // 73728B

    const int tid  = threadIdx.x;
    const int lane = tid & 63;

    if (blockIdx.x < 8) {
        // ================= recur path (R10, byte-for-byte logic) ==========
        unsigned short* cbf0 = (unsigned short*)smem;          // [16*256]
        unsigned short* cbf1 = (unsigned short*)smem + 16 * 256;

        const int dir = blockIdx.x >> 2;
        const int bg  = blockIdx.x & 3;
        const int b0  = bg * 16;
        const int wl  = tid >> 6;
        const int col = lane & 15;
        const int g   = lane >> 4;

        const float* W   = dir ? Wr : Wl;
        const float* c0  = dir ? cr0 : cl0;
        const float* pre = dir ? pre2_r : pre2_l;
        unsigned short* out = dir ? outr : outl;

        bf16x8 wfrag[4][8];
#pragma unroll
        for (int mt = 0; mt < 4; ++mt)
#pragma unroll
            for (int i = 0; i < 8; ++i) {
                const int kt = (i + 2 * wl) & 7;
                const float* src = W + (size_t)(wl * 64 + mt * 16 + col) * DD
                                     + kt * 32 + g * 8;
                const float4 lo = *(const float4*)(src);
                const float4 hi = *(const float4*)(src + 4);
                ush8 p;
                p[0]=f2bf(lo.x); p[1]=f2bf(lo.y); p[2]=f2bf(lo.z); p[3]=f2bf(lo.w);
                p[4]=f2bf(hi.x); p[5]=f2bf(hi.y); p[6]=f2bf(hi.z); p[7]=f2bf(hi.w);
                wfrag[mt][i] = *(bf16x8*)&p;
            }

        int soff[8];
#pragma unroll
        for (int i = 0; i < 8; ++i) {
            const int kt = (i + 2 * wl) & 7;
            soff[i] = CSWZ(col, kt * 64 + g * 16);
        }

        {
            const int blc = tid >> 4;
            const int ch  = tid & 15;
            const float* src = c0 + (size_t)(b0 + blc) * DD + ch * 16;
            const float4 v0 = *(const float4*)(src);
            const float4 v1 = *(const float4*)(src + 4);
            const float4 v2 = *(const float4*)(src + 8);
            const float4 v3 = *(const float4*)(src + 12);
            ush8 p0, p1;
            p0[0]=f2bf(v0.x); p0[1]=f2bf(v0.y); p0[2]=f2bf(v0.z); p0[3]=f2bf(v0.w);
            p0[4]=f2bf(v1.x); p0[5]=f2bf(v1.y); p0[6]=f2bf(v1.z); p0[7]=f2bf(v1.w);
            p1[0]=f2bf(v2.x); p1[1]=f2bf(v2.y); p1[2]=f2bf(v2.z); p1[3]=f2bf(v2.w);
            p1[4]=f2bf(v3.x); p1[5]=f2bf(v3.y); p1[6]=f2bf(v3.z); p1[7]=f2bf(v3.w);
            char* rowp = (char*)cbf0 + blc * 512;
            *(ush8*)(rowp + CSWZ(blc, ch * 32))      = p0;
            *(ush8*)(rowp + CSWZ(blc, ch * 32 + 16)) = p1;
            const int t0 = dir ? 511 : 0;
            ush8* dst = (ush8*)(out + ((size_t)t0 * BB + b0 + blc) * DD + ch * 16);
            dst[0] = p0; dst[1] = p1;
        }

        const int lpre = (wl * 16 + g) * 64 + col * 4;
        const ptrdiff_t pstep = dir ? -(ptrdiff_t)16384 : (ptrdiff_t)16384;
        const float* p0 = pre + ((size_t)(dir ? 511 : 0) * 4 + bg) * 4096 + lpre;

        float4 pA0 = *(const float4*)(p0);
        float4 pA1 = *(const float4*)(p0 + 256);
        float4 pA2 = *(const float4*)(p0 + 512);
        float4 pA3 = *(const float4*)(p0 + 768);
        const float* p1p = p0 + pstep;
        float4 pB0 = *(const float4*)(p1p);
        float4 pB1 = *(const float4*)(p1p + 256);
        float4 pB2 = *(const float4*)(p1p + 512);
        float4 pB3 = *(const float4*)(p1p + 768);
        const float* pfetch = p0 + 2 * pstep;

        unsigned short* oplane = out + (size_t)(dir ? 510 : 1) * BB * DD
                                     + (b0 + col) * DD + wl * 64 + g * 4;
        const ptrdiff_t ostep = (dir ? -(ptrdiff_t)1 : (ptrdiff_t)1) * (BB * DD);

        __syncthreads();

        int cur = 0;
#pragma unroll 2
        for (int k = 0; k < SS - 1; ++k) {
            bf16x8 sfrag[8];
            {
                const char* rowp = (const char*)(cur ? cbf1 : cbf0) + col * 512;
#pragma unroll
                for (int i = 0; i < 8; ++i)
                    sfrag[i] = *(const bf16x8*)(rowp + soff[i]);
            }

            const float4 pN0 = *(const float4*)(pfetch);
            const float4 pN1 = *(const float4*)(pfetch + 256);
            const float4 pN2 = *(const float4*)(pfetch + 512);
            const float4 pN3 = *(const float4*)(pfetch + 768);
            if (k < SS - 4) pfetch += pstep;

            char* nbuf = (char*)(cur ? cbf0 : cbf1) + col * 512;

            auto epi = [&](int mt, const f32x4 a) {
                const float v0 = fmaxf(a[0], 0.f);
                const float v1 = fmaxf(a[1], 0.f);
                const float v2 = fmaxf(a[2], 0.f);
                const float v3 = fmaxf(a[3], 0.f);
                uint2 uu;
                asm("v_cvt_pk_bf16_f32 %0, %1, %2" : "=v"(uu.x) : "v"(v0), "v"(v1));
                asm("v_cvt_pk_bf16_f32 %0, %1, %2" : "=v"(uu.y) : "v"(v2), "v"(v3));
                const int eoff = (wl * 64 + mt * 16 + g * 4) * 2;
                *(uint2*)(nbuf + CSWZ(col, eoff)) = uu;
                *(uint2*)(oplane + mt * 16) = uu;
            };

            f32x4 a0 = *(const f32x4*)&pA0;
            f32x4 a1 = *(const f32x4*)&pA1;
            __builtin_amdgcn_s_setprio(1);
#pragma unroll
            for (int i = 0; i < 8; ++i) {
                a0 = __builtin_amdgcn_mfma_f32_16x16x32_bf16(wfrag[0][i], sfrag[i], a0, 0, 0, 0);
                a1 = __builtin_amdgcn_mfma_f32_16x16x32_bf16(wfrag[1][i], sfrag[i], a1, 0, 0, 0);
            }
            __builtin_amdgcn_s_setprio(0);
            epi(0, a0);
            epi(1, a1);

            f32x4 a2 = *(const f32x4*)&pA2;
            f32x4 a3 = *(const f32x4*)&pA3;
            __builtin_amdgcn_s_setprio(1);
#pragma unroll
            for (int i = 0; i < 8; ++i) {
                a2 = __builtin_amdgcn_mfma_f32_16x16x32_bf16(wfrag[2][i], sfrag[i], a2, 0, 0, 0);
                a3 = __builtin_amdgcn_mfma_f32_16x16x32_bf16(wfrag[3][i], sfrag[i], a3, 0, 0, 0);
            }
            __builtin_amdgcn_s_setprio(0);
            epi(2, a2);
            epi(3, a3);

            pA0 = pB0; pA1 = pB1; pA2 = pB2; pA3 = pB3;
            pB0 = pN0; pB1 = pN1; pB2 = pN2; pB3 = pN3;
            oplane += ostep;

            asm volatile("s_waitcnt lgkmcnt(0)" ::: "memory");
            __builtin_amdgcn_s_barrier();
            asm volatile("" ::: "memory");
            cur ^= 1;
        }
        return;
    }

    // ===================== conv_e path (blocks 8..135) =====================
    unsigned short* Ab = (unsigned short*)smem;                    // [2][128][APAD]
    unsigned short* Bb = (unsigned short*)smem + 2 * 128 * APAD;

    const int wid = tid >> 6;
    const int lr  = lane & 15;
    const int lk  = (lane >> 4) * 8;
    const int strow = tid >> 3;
    const int skc   = (tid & 7) * 8;

    for (int rep = 0; rep < 2; ++rep) {
        const int cid = (blockIdx.x - 8) + rep * 128;
        const int b   = cid >> 2;
        const int h0  = (cid & 3) * 128;

        f32x4 acc[2][8];
#pragma unroll
        for (int st = 0; st < 2; ++st)
#pragma unroll
            for (int ht = 0; ht < 8; ++ht) acc[st][ht] = (f32x4)(0.f);

        auto stage = [&](int it, int buf) {
            const int stile = it >> 2, kstep = it & 3;
            const int k0 = kstep * 64;
            const int s0 = stile * 128;
#pragma unroll
            for (int j = 0; j < 4; ++j) {
                const int row = strow + 32 * j;
                const int ss = s0 + row;
                *(bf16x8*)&Ab[(buf * 128 + row) * APAD + skc] =
                    *(const bf16x8*)(e2 + ((size_t)ss * BB + b) * DD + k0 + skc);
                *(bf16x8*)&Bb[(buf * 128 + row) * APAD + skc] =
                    *(const bf16x8*)(convwb + (size_t)(h0 + row) * K3D + 256 + k0 + skc);
            }
        };

        stage(0, 0);
        int cur = 0;
        for (int it = 0; it < 16; ++it) {
            __syncthreads();
            if (it + 1 < 16) stage(it + 1, cur ^ 1);

            const int wrow0 = wid * 32;
#pragma unroll
            for (int ks = 0; ks < 2; ++ks) {
                const int kk = ks * 32 + lk;
                const bf16x8 a0 = *(const bf16x8*)&Ab[(cur * 128 + wrow0 + lr) * APAD + kk];
                const bf16x8 a1 = *(const bf16x8*)&Ab[(cur * 128 + wrow0 + 16 + lr) * APAD + kk];
#pragma unroll
                for (int ht = 0; ht < 8; ++ht) {
                    const bf16x8 bv = *(const bf16x8*)&Bb[(cur * 128 + ht * 16 + lr) * APAD + kk];
                    acc[0][ht] = __builtin_amdgcn_mfma_f32_16x16x32_bf16(a0, bv, acc[0][ht], 0, 0, 0);
                    acc[1][ht] = __builtin_amdgcn_mfma_f32_16x16x32_bf16(a1, bv, acc[1][ht], 0, 0, 0);
                }
            }
            if ((it & 3) == 3) {   // s-tile K done: dump partials, reset acc
                const int stile = it >> 2;
                unsigned short* hp = hpart + (size_t)(cid * 4 + stile) * 16384;
#pragma unroll
                for (int st = 0; st < 2; ++st)
#pragma unroll
                    for (int ht = 0; ht < 8; ++ht) {
                        uint2 uu;
                        asm("v_cvt_pk_bf16_f32 %0, %1, %2"
                            : "=v"(uu.x) : "v"(acc[st][ht][0]), "v"(acc[st][ht][1]));
                        asm("v_cvt_pk_bf16_f32 %0, %1, %2"
                            : "=v"(uu.y) : "v"(acc[st][ht][2]), "v"(acc[st][ht][3]));
                        const int f = (wid * 2 + st) * 8 + ht;
                        *(uint2*)(hp + f * 256 + lane * 4) = uu;
                        acc[st][ht] = (f32x4)(0.f);
                    }
            }
            cur ^= 1;
        }
        __syncthreads();
    }
}

// ---------------------------------------------------------------------------
// Kernel 3: conv(left|right) + hpart(e) + relu + maxpool.
// K = 512 (8 steps); acc initialized from hpart fragments (e-contribution).
// ---------------------------------------------------------------------------
#define KSTEP 64
#define NKC 8
#define NST 4

__global__ __launch_bounds__(256) void conv_pool_kernel(
    const unsigned short* __restrict__ leftb,
    const unsigned short* __restrict__ rightb,
    const unsigned short* __restrict__ convwb,
    const unsigned short* __restrict__ hpart,
    const float* __restrict__ conv_b,
    float* __restrict__ pooled)
{
    __shared__ unsigned short Abuf[2][128][APAD];
    __shared__ unsigned short Bbuf[2][128][APAD];
    __shared__ float red[4][128];

    const int b   = blockIdx.x >> 2;
    const int h0  = (blockIdx.x & 3) * 128;
    const int tid = threadIdx.x;
    const int wid = tid >> 6;
    const int lane = tid & 63;
    const int lr  = lane & 15;
    const int lk  = (lane >> 4) * 8;

    float pmax[8];
#pragma unroll
    for (int ht = 0; ht < 8; ++ht) pmax[ht] = -INFINITY;

    const int strow = tid >> 3;
    const int skc   = (tid & 7) * 8;

    auto stage = [&](int it, int buf) {
        const int stile = it / NKC, kstep = it % NKC;
        const int k0 = kstep * KSTEP;
        const int s0 = stile * 128;
        const unsigned short* asrc;
        int koff, bcol;
        if (k0 < DD) { asrc = leftb;  koff = k0;      bcol = k0; }
        else         { asrc = rightb; koff = k0 - DD; bcol = k0 + 256; }
#pragma unroll
        for (int j = 0; j < 4; ++j) {
            const int row = strow + 32 * j;
            const int ss = s0 + row;
            *(bf16x8*)&Abuf[buf][row][skc] =
                *(const bf16x8*)(asrc + ((size_t)ss * BB + b) * DD + koff + skc);
            *(bf16x8*)&Bbuf[buf][row][skc] =
                *(const bf16x8*)(convwb + (size_t)(h0 + row) * K3D + bcol + skc);
        }
    };

    f32x4 acc[2][8];
    auto load_hinit = [&](int stile) {
        const unsigned short* hp = hpart + (size_t)(blockIdx.x * 4 + stile) * 16384;
#pragma unroll
        for (int st = 0; st < 2; ++st)
#pragma unroll
            for (int ht = 0; ht < 8; ++ht) {
                const int f = (wid * 2 + st) * 8 + ht;
                const uint2 uu = *(const uint2*)(hp + f * 256 + lane * 4);
                f32x4 v;
                v[0] = __uint_as_float(uu.x << 16);
                v[1] = __uint_as_float(uu.x & 0xffff0000u);
                v[2] = __uint_as_float(uu.y << 16);
                v[3] = __uint_as_float(uu.y & 0xffff0000u);
                acc[st][ht] = v;
            }
    };

    load_hinit(0);
    stage(0, 0);
    int cur = 0;
    for (int it = 0; it < NST * NKC; ++it) {
        __syncthreads();
        if (it + 1 < NST * NKC) stage(it + 1, cur ^ 1);

        const int wrow0 = wid * 32;
#pragma unroll
        for (int ks = 0; ks < 2; ++ks) {
            const int kk = ks * 32 + lk;
            const bf16x8 a0 = *(const bf16x8*)&Abuf[cur][wrow0 + lr][kk];
            const bf16x8 a1 = *(const bf16x8*)&Abuf[cur][wrow0 + 16 + lr][kk];
#pragma unroll
            for (int ht = 0; ht < 8; ++ht) {
                const bf16x8 bv = *(const bf16x8*)&Bbuf[cur][ht * 16 + lr][kk];
                acc[0][ht] = __builtin_amdgcn_mfma_f32_16x16x32_bf16(a0, bv, acc[0][ht], 0, 0, 0);
                acc[1][ht] = __builtin_amdgcn_mfma_f32_16x16x32_bf16(a1, bv, acc[1][ht], 0, 0, 0);
            }
        }
        if ((it % NKC) == NKC - 1) {
#pragma unroll
            for (int st = 0; st < 2; ++st)
#pragma unroll
                for (int ht = 0; ht < 8; ++ht)
#pragma unroll
                    for (int r = 0; r < 4; ++r)
                        pmax[ht] = fmaxf(pmax[ht], acc[st][ht][r]);
            if (it + 1 < NST * NKC) load_hinit((it + 1) / NKC);
        }
        cur ^= 1;
    }

#pragma unroll
    for (int ht = 0; ht < 8; ++ht) {
        float m = pmax[ht];
        m = fmaxf(m, __shfl_xor(m, 16));
        m = fmaxf(m, __shfl_xor(m, 32));
        if (lane < 16) red[wid][ht * 16 + lane] = m;
    }
    __syncthreads();
    if (tid < 128) {
        const float m = fmaxf(fmaxf(red[0][tid], red[1][tid]),
                              fmaxf(red[2][tid], red[3][tid]));
        pooled[(size_t)b * HH + h0 + tid] = fmaxf(m + conv_b[h0 + tid], 0.f);
    }
}

// ---------------------------------------------------------------------------
// Kernel 4: final FC (unchanged).
// ---------------------------------------------------------------------------
__global__ void fc_kernel(const float* __restrict__ pooled,
                          const float* __restrict__ fc_w,
                          const float* __restrict__ fc_b,
                          float* __restrict__ out)
{
    const int t = threadIdx.x;
    if (t >= BB * NCLS) return;
    const int b = t / NCLS, c = t % NCLS;
    float acc = fc_b[c];
    for (int h = 0; h < HH; ++h)
        acc += pooled[(size_t)b * HH + h] * fc_w[(size_t)c * HH + h];
    out[b * NCLS + c] = acc;
}

// ---------------------------------------------------------------------------
extern "C" void kernel_launch(void* const* d_in, const int* in_sizes, int n_in,
                              void* d_out, int out_size, void* d_ws, size_t ws_size,
                              hipStream_t stream)
{
    const int*   x       = (const int*)  d_in[0];
    const float* embed_w = (const float*)d_in[1];
    const float* Wl      = (const float*)d_in[2];
    const float* bl      = (const float*)d_in[3];
    const float* Wsl     = (const float*)d_in[4];
    const float* bsl     = (const float*)d_in[5];
    const float* Wr      = (const float*)d_in[6];
    const float* br      = (const float*)d_in[7];
    const float* Wsr     = (const float*)d_in[8];
    const float* bsr     = (const float*)d_in[9];
    const float* conv_w  = (const float*)d_in[10];
    const float* conv_b  = (const float*)d_in[11];
    const float* fc_w    = (const float*)d_in[12];
    const float* fc_b    = (const float*)d_in[13];
    const float* cl0     = (const float*)d_in[14];
    const float* cr0     = (const float*)d_in[15];
    float* out = (float*)d_out;

    char* ws = (char*)d_ws;
    const size_t SZf = (size_t)SS * BB * DD * sizeof(float);           // 33.55 MB
    const size_t SZh = (size_t)SS * BB * DD * sizeof(unsigned short);  // 16.78 MB
    float*          pre2_l = (float*)(ws);
    float*          pre2_r = (float*)(ws + SZf);
    unsigned short* leftb  = (unsigned short*)(ws + 2 * SZf);
    unsigned short* rightb = (unsigned short*)(ws + 2 * SZf + SZh);
    unsigned short* e2     = (unsigned short*)(ws + 2 * SZf + 2 * SZh);
    unsigned short* convwb = (unsigned short*)(ws + 2 * SZf + 3 * SZh);
    unsigned short* wscat  = (unsigned short*)(ws + 2 * SZf + 3 * SZh + (size_t)HH * K3D * 2);
    float*          biascat= (float*)(ws + 2 * SZf + 3 * SZh + (size_t)HH * K3D * 2 + (size_t)512 * DD * 2);
    float*          pooled = (float*)(ws + 2 * SZf + 3 * SZh + (size_t)HH * K3D * 2 + (size_t)512 * DD * 2 + 2048);
    unsigned short* hpart  = (unsigned short*)(ws + 2 * SZf + 3 * SZh + (size_t)HH * K3D * 2 + (size_t)512 * DD * 2 + 2048 + (size_t)BB * HH * 4);

    prep_gather_kernel<<<257 + (BB * SS * DD / 8) / 256, 256, 0, stream>>>(
        conv_w, Wsl, Wsr, bsl, bl, bsr, br, x, embed_w,
        convwb, wscat, biascat, e2);

    pre_mfma_kernel<<<1024, 256, 0, stream>>>(wscat, e2, biascat, pre2_l, pre2_r);

    recur_conve_kernel<<<136, 256, 0, stream>>>(
        Wl, Wr, cl0, cr0, pre2_l, pre2_r, leftb, rightb, e2, convwb, hpart);

    conv_pool_kernel<<<BB * (HH / 128), 256, 0, stream>>>(
        leftb, rightb, convwb, hpart, conv_b, pooled);

    fc_kernel<<<1, BB * NCLS, 0, stream>>>(pooled, fc_w, fc_b, out);
}

// Round 12
// 437.689 us; speedup vs baseline: 1.8622x; 1.0213x over previous
//
#include <hip/hip_runtime.h>
#include <hip/hip_bf16.h>

#define VOCAB 50000
#define DD 256
#define NCLS 10
#define BB 64
#define SS 512
#define HH 512
#define K3D 768

typedef __attribute__((ext_vector_type(8))) short bf16x8;
typedef __attribute__((ext_vector_type(8))) unsigned short ush8;
typedef __attribute__((ext_vector_type(4))) float f32x4;

static __device__ __forceinline__ unsigned short f2bf(float f) {
    __hip_bfloat16 h = __float2bfloat16(f);
    return *reinterpret_cast<unsigned short*>(&h);
}

static __device__ __forceinline__ ush8 cvt8(const float* src) {
    const float4 lo = *(const float4*)(src);
    const float4 hi = *(const float4*)(src + 4);
    ush8 o;
    o[0]=f2bf(lo.x); o[1]=f2bf(lo.y); o[2]=f2bf(lo.z); o[3]=f2bf(lo.w);
    o[4]=f2bf(hi.x); o[5]=f2bf(hi.y); o[6]=f2bf(hi.z); o[7]=f2bf(hi.w);
    return o;
}

// ---------------------------------------------------------------------------
// Kernel 1: prep + gather + pre-GEMM merged (block-range partitioned; the
// three parts have no inter-dependencies).
//   bid < 1024 : pre-GEMM MFMA, staging DIRECTLY from fp32 Wsl/Wsr and
//                embed_w (gather via xs[] LDS table); biases read raw.
//   bid < 1216 : conv_w -> bf16 (convwb)
//   else       : embedding gather -> bf16 e2[s*64+b][d]  (4096 blocks)
// ---------------------------------------------------------------------------
#define PPAD 72

__global__ __launch_bounds__(256) void prep_pre_kernel(
    const float* __restrict__ Wsl, const float* __restrict__ Wsr,
    const float* __restrict__ bsl, const float* __restrict__ bl,
    const float* __restrict__ bsr, const float* __restrict__ br,
    const int* __restrict__ x, const float* __restrict__ embed_w,
    const float* __restrict__ conv_w,
    unsigned short* __restrict__ convwb,
    unsigned short* __restrict__ e2,
    float* __restrict__ pre2_l, float* __restrict__ pre2_r)
{
    __shared__ unsigned short Abuf[2][128][PPAD];
    __shared__ unsigned short Bbuf[2][128][PPAD];
    __shared__ int xs[128];

    const int bid = blockIdx.x;
    const int tid = threadIdx.x;

    if (bid < 1024) {
        // ---------------- pre-GEMM path ----------------
        const int mi  = bid & 3;
        const int sbi = bid >> 2;
        const int w = tid >> 6, lane = tid & 63;
        const int lr = lane & 15, g = lane >> 4;
        const int lk = g * 8;
        const int strow = tid >> 3;
        const int skc   = (tid & 7) * 8;

        if (tid < 128)
            xs[tid] = x[(tid & 63) * SS + 2 * sbi + (tid >> 6)];

        f32x4 acc[2][8];
#pragma unroll
        for (int mt = 0; mt < 2; ++mt)
#pragma unroll
            for (int nt = 0; nt < 8; ++nt) acc[mt][nt] = (f32x4)(0.f);

        auto stage = [&](int ks, int buf) {
            const int k0 = ks * 64;
#pragma unroll
            for (int j = 0; j < 4; ++j) {
                const int row = strow + 32 * j;
                const float* wsrc = (mi < 2 ? Wsl + (size_t)(mi * 128 + row) * DD
                                            : Wsr + (size_t)((mi - 2) * 128 + row) * DD)
                                    + k0 + skc;
                *(ush8*)&Abuf[buf][row][skc] = cvt8(wsrc);
                const float* esrc = embed_w + (size_t)xs[row] * DD + k0 + skc;
                *(ush8*)&Bbuf[buf][row][skc] = cvt8(esrc);
            }
        };

        __syncthreads();   // xs visible
        stage(0, 0);
        int cur = 0;
        for (int ks = 0; ks < 4; ++ks) {
            __syncthreads();
            if (ks + 1 < 4) stage(ks + 1, cur ^ 1);
#pragma unroll
            for (int k2 = 0; k2 < 2; ++k2) {
                const int kk = k2 * 32 + lk;
                const bf16x8 a0 = *(const bf16x8*)&Abuf[cur][w * 32 + lr][kk];
                const bf16x8 a1 = *(const bf16x8*)&Abuf[cur][w * 32 + 16 + lr][kk];
#pragma unroll
                for (int nt = 0; nt < 8; ++nt) {
                    const bf16x8 bv = *(const bf16x8*)&Bbuf[cur][nt * 16 + lr][kk];
                    acc[0][nt] = __builtin_amdgcn_mfma_f32_16x16x32_bf16(a0, bv, acc[0][nt], 0, 0, 0);
                    acc[1][nt] = __builtin_amdgcn_mfma_f32_16x16x32_bf16(a1, bv, acc[1][nt], 0, 0, 0);
                }
            }
            cur ^= 1;
        }

#pragma unroll
        for (int mt = 0; mt < 2; ++mt) {
            const int eg = mi * 128 + w * 32 + mt * 16 + g * 4;
            const int e  = eg & 255;
            const float* bsx = (eg < 256) ? bsl : bsr;
            const float* bbx = (eg < 256) ? bl  : br;
            const float4 b1 = *(const float4*)(bsx + e);
            const float4 b2 = *(const float4*)(bbx + e);
            float* dstb = (eg >= 256) ? pre2_r : pre2_l;
#pragma unroll
            for (int nt = 0; nt < 8; ++nt) {
                const int sb = sbi * 128 + nt * 16 + lr;
                const int s = sb >> 6, bgq = (sb >> 4) & 3, b_loc = sb & 15;
                float4 v;
                v.x = acc[mt][nt][0] + b1.x + b2.x;
                v.y = acc[mt][nt][1] + b1.y + b2.y;
                v.z = acc[mt][nt][2] + b1.z + b2.z;
                v.w = acc[mt][nt][3] + b1.w + b2.w;
                *(float4*)(dstb + ((size_t)s * 4 + bgq) * 4096 + (e >> 2) * 64 + b_loc * 4) = v;
            }
        }
    } else if (bid < 1216) {
        // ---------------- conv_w -> bf16 ----------------
        const int g = (bid - 1024) * 256 + tid;
        *(ush8*)(convwb + (size_t)g * 8) = cvt8(conv_w + (size_t)g * 8);
    } else {
        // ---------------- embedding gather ----------------
        const int g = (bid - 1216) * 256 + tid;
        const int bs = g >> 5;                         // b*S + s
        const int b = bs >> 9, s = bs & (SS - 1);
        const int d0 = (g & 31) * 8;
        *(ush8*)(e2 + ((size_t)s * BB + b) * DD + d0) =
            cvt8(embed_w + (size_t)x[bs] * DD + d0);
    }
}

// ---------------------------------------------------------------------------
// Kernel 2: FUSED recur (blocks 0..7, frozen R10 structure) + conv_e
// (blocks 8..135): h_e partials = e2 @ conv_w[:,256:512]^T -> hpart (bf16).
// ---------------------------------------------------------------------------
#define CSWZ(row, off) ((off) ^ (((row) & 15) << 4))
#define APAD 72

__global__ __launch_bounds__(256, 1) void recur_conve_kernel(
    const float* __restrict__ Wl, const float* __restrict__ Wr,
    const float* __restrict__ cl0, const float* __restrict__ cr0,
    const float* __restrict__ pre2_l, const float* __restrict__ pre2_r,
    unsigned short* __restrict__ outl, unsigned short* __restrict__ outr,
    const unsigned short* __restrict__ e2,
    const unsigned short* __restrict__ convwb,
    unsigned short* __restrict__ hpart)
{
    __shared__ alignas(16) unsigned char smem[2 * 2 * 128 * APAD * 2];  // 73728B

    const int tid  = threadIdx.x;
    const int lane = tid & 63;

    if (blockIdx.x < 8) {
        // ================= recur path ==========
        unsigned short* cbf0 = (unsigned short*)smem;          // [16*256]
        unsigned short* cbf1 = (unsigned short*)smem + 16 * 256;

        const int dir = blockIdx.x >> 2;
        const int bg  = blockIdx.x & 3;
        const int b0  = bg * 16;
        const int wl  = tid >> 6;
        const int col = lane & 15;
        const int g   = lane >> 4;

        const float* W   = dir ? Wr : Wl;
        const float* c0  = dir ? cr0 : cl0;
        const float* pre = dir ? pre2_r : pre2_l;
        unsigned short* out = dir ? outr : outl;

        bf16x8 wfrag[4][8];
#pragma unroll
        for (int mt = 0; mt < 4; ++mt)
#pragma unroll
            for (int i = 0; i < 8; ++i) {
                const int kt = (i + 2 * wl) & 7;
                const float* src = W + (size_t)(wl * 64 + mt * 16 + col) * DD
                                     + kt * 32 + g * 8;
                const ush8 p = cvt8(src);
                wfrag[mt][i] = *(bf16x8*)&p;
            }

        int soff[8];
#pragma unroll
        for (int i = 0; i < 8; ++i) {
            const int kt = (i + 2 * wl) & 7;
            soff[i] = CSWZ(col, kt * 64 + g * 16);
        }

        {
            const int blc = tid >> 4;
            const int ch  = tid & 15;
            const float* src = c0 + (size_t)(b0 + blc) * DD + ch * 16;
            const ush8 p0 = cvt8(src);
            const ush8 p1 = cvt8(src + 8);
            char* rowp = (char*)cbf0 + blc * 512;
            *(ush8*)(rowp + CSWZ(blc, ch * 32))      = p0;
            *(ush8*)(rowp + CSWZ(blc, ch * 32 + 16)) = p1;
            const int t0 = dir ? 511 : 0;
            ush8* dst = (ush8*)(out + ((size_t)t0 * BB + b0 + blc) * DD + ch * 16);
            dst[0] = p0; dst[1] = p1;
        }

        const int lpre = (wl * 16 + g) * 64 + col * 4;
        const ptrdiff_t pstep = dir ? -(ptrdiff_t)16384 : (ptrdiff_t)16384;
        const float* p0 = pre + ((size_t)(dir ? 511 : 0) * 4 + bg) * 4096 + lpre;

        float4 pA0 = *(const float4*)(p0);
        float4 pA1 = *(const float4*)(p0 + 256);
        float4 pA2 = *(const float4*)(p0 + 512);
        float4 pA3 = *(const float4*)(p0 + 768);
        const float* p1p = p0 + pstep;
        float4 pB0 = *(const float4*)(p1p);
        float4 pB1 = *(const float4*)(p1p + 256);
        float4 pB2 = *(const float4*)(p1p + 512);
        float4 pB3 = *(const float4*)(p1p + 768);
        const float* pfetch = p0 + 2 * pstep;

        unsigned short* oplane = out + (size_t)(dir ? 510 : 1) * BB * DD
                                     + (b0 + col) * DD + wl * 64 + g * 4;
        const ptrdiff_t ostep = (dir ? -(ptrdiff_t)1 : (ptrdiff_t)1) * (BB * DD);

        __syncthreads();

        int cur = 0;
#pragma unroll 2
        for (int k = 0; k < SS - 1; ++k) {
            bf16x8 sfrag[8];
            {
                const char* rowp = (const char*)(cur ? cbf1 : cbf0) + col * 512;
#pragma unroll
                for (int i = 0; i < 8; ++i)
                    sfrag[i] = *(const bf16x8*)(rowp + soff[i]);
            }

            const float4 pN0 = *(const float4*)(pfetch);
            const float4 pN1 = *(const float4*)(pfetch + 256);
            const float4 pN2 = *(const float4*)(pfetch + 512);
            const float4 pN3 = *(const float4*)(pfetch + 768);
            if (k < SS - 4) pfetch += pstep;

            char* nbuf = (char*)(cur ? cbf0 : cbf1) + col * 512;

            auto epi = [&](int mt, const f32x4 a) {
                const float v0 = fmaxf(a[0], 0.f);
                const float v1 = fmaxf(a[1], 0.f);
                const float v2 = fmaxf(a[2], 0.f);
                const float v3 = fmaxf(a[3], 0.f);
                uint2 uu;
                asm("v_cvt_pk_bf16_f32 %0, %1, %2" : "=v"(uu.x) : "v"(v0), "v"(v1));
                asm("v_cvt_pk_bf16_f32 %0, %1, %2" : "=v"(uu.y) : "v"(v2), "v"(v3));
                const int eoff = (wl * 64 + mt * 16 + g * 4) * 2;
                *(uint2*)(nbuf + CSWZ(col, eoff)) = uu;
                *(uint2*)(oplane + mt * 16) = uu;
            };

            f32x4 a0 = *(const f32x4*)&pA0;
            f32x4 a1 = *(const f32x4*)&pA1;
            __builtin_amdgcn_s_setprio(1);
#pragma unroll
            for (int i = 0; i < 8; ++i) {
                a0 = __builtin_amdgcn_mfma_f32_16x16x32_bf16(wfrag[0][i], sfrag[i], a0, 0, 0, 0);
                a1 = __builtin_amdgcn_mfma_f32_16x16x32_bf16(wfrag[1][i], sfrag[i], a1, 0, 0, 0);
            }
            __builtin_amdgcn_s_setprio(0);
            epi(0, a0);
            epi(1, a1);

            f32x4 a2 = *(const f32x4*)&pA2;
            f32x4 a3 = *(const f32x4*)&pA3;
            __builtin_amdgcn_s_setprio(1);
#pragma unroll
            for (int i = 0; i < 8; ++i) {
                a2 = __builtin_amdgcn_mfma_f32_16x16x32_bf16(wfrag[2][i], sfrag[i], a2, 0, 0, 0);
                a3 = __builtin_amdgcn_mfma_f32_16x16x32_bf16(wfrag[3][i], sfrag[i], a3, 0, 0, 0);
            }
            __builtin_amdgcn_s_setprio(0);
            epi(2, a2);
            epi(3, a3);

            pA0 = pB0; pA1 = pB1; pA2 = pB2; pA3 = pB3;
            pB0 = pN0; pB1 = pN1; pB2 = pN2; pB3 = pN3;
            oplane += ostep;

            asm volatile("s_waitcnt lgkmcnt(0)" ::: "memory");
            __builtin_amdgcn_s_barrier();
            asm volatile("" ::: "memory");
            cur ^= 1;
        }
        return;
    }

    // ===================== conv_e path (blocks 8..135) =====================
    unsigned short* Ab = (unsigned short*)smem;                    // [2][128][APAD]
    unsigned short* Bb = (unsigned short*)smem + 2 * 128 * APAD;

    const int wid = tid >> 6;
    const int lr  = lane & 15;
    const int lk  = (lane >> 4) * 8;
    const int strow = tid >> 3;
    const int skc   = (tid & 7) * 8;

    for (int rep = 0; rep < 2; ++rep) {
        const int cid = (blockIdx.x - 8) + rep * 128;
        const int b   = cid >> 2;
        const int h0  = (cid & 3) * 128;

        f32x4 acc[2][8];
#pragma unroll
        for (int st = 0; st < 2; ++st)
#pragma unroll
            for (int ht = 0; ht < 8; ++ht) acc[st][ht] = (f32x4)(0.f);

        auto stage = [&](int it, int buf) {
            const int stile = it >> 2, kstep = it & 3;
            const int k0 = kstep * 64;
            const int s0 = stile * 128;
#pragma unroll
            for (int j = 0; j < 4; ++j) {
                const int row = strow + 32 * j;
                const int ss = s0 + row;
                *(bf16x8*)&Ab[(buf * 128 + row) * APAD + skc] =
                    *(const bf16x8*)(e2 + ((size_t)ss * BB + b) * DD + k0 + skc);
                *(bf16x8*)&Bb[(buf * 128 + row) * APAD + skc] =
                    *(const bf16x8*)(convwb + (size_t)(h0 + row) * K3D + 256 + k0 + skc);
            }
        };

        stage(0, 0);
        int cur = 0;
        for (int it = 0; it < 16; ++it) {
            __syncthreads();
            if (it + 1 < 16) stage(it + 1, cur ^ 1);

            const int wrow0 = wid * 32;
#pragma unroll
            for (int ks = 0; ks < 2; ++ks) {
                const int kk = ks * 32 + lk;
                const bf16x8 a0 = *(const bf16x8*)&Ab[(cur * 128 + wrow0 + lr) * APAD + kk];
                const bf16x8 a1 = *(const bf16x8*)&Ab[(cur * 128 + wrow0 + 16 + lr) * APAD + kk];
#pragma unroll
                for (int ht = 0; ht < 8; ++ht) {
                    const bf16x8 bv = *(const bf16x8*)&Bb[(cur * 128 + ht * 16 + lr) * APAD + kk];
                    acc[0][ht] = __builtin_amdgcn_mfma_f32_16x16x32_bf16(a0, bv, acc[0][ht], 0, 0, 0);
                    acc[1][ht] = __builtin_amdgcn_mfma_f32_16x16x32_bf16(a1, bv, acc[1][ht], 0, 0, 0);
                }
            }
            if ((it & 3) == 3) {
                const int stile = it >> 2;
                unsigned short* hp = hpart + (size_t)(cid * 4 + stile) * 16384;
#pragma unroll
                for (int st = 0; st < 2; ++st)
#pragma unroll
                    for (int ht = 0; ht < 8; ++ht) {
                        uint2 uu;
                        asm("v_cvt_pk_bf16_f32 %0, %1, %2"
                            : "=v"(uu.x) : "v"(acc[st][ht][0]), "v"(acc[st][ht][1]));
                        asm("v_cvt_pk_bf16_f32 %0, %1, %2"
                            : "=v"(uu.y) : "v"(acc[st][ht][2]), "v"(acc[st][ht][3]));
                        const int f = (wid * 2 + st) * 8 + ht;
                        *(uint2*)(hp + f * 256 + lane * 4) = uu;
                        acc[st][ht] = (f32x4)(0.f);
                    }
            }
            cur ^= 1;
        }
        __syncthreads();
    }
}

// ---------------------------------------------------------------------------
// Kernel 3: conv(left|right) + hpart(e) + relu + maxpool.
// grid = 1024: (b, h0, stile) — 4 s-tiles per (b,h0) run as SEPARATE blocks
// (2 blocks/CU occupancy vs 1 before); per-block partial max merged into
// pooled via uint atomicMax (values >= 0, relu(x+b) monotone => correct).
// ---------------------------------------------------------------------------
#define KSTEP 64
#define NKC 8

__global__ __launch_bounds__(256) void conv_pool_kernel(
    const unsigned short* __restrict__ leftb,
    const unsigned short* __restrict__ rightb,
    const unsigned short* __restrict__ convwb,
    const unsigned short* __restrict__ hpart,
    const float* __restrict__ conv_b,
    float* __restrict__ pooled)
{
    __shared__ unsigned short Abuf[2][128][APAD];
    __shared__ unsigned short Bbuf[2][128][APAD];
    __shared__ float red[4][128];

    const int stile = blockIdx.x & 3;
    const int h0i   = (blockIdx.x >> 2) & 3;
    const int b     = blockIdx.x >> 4;
    const int h0    = h0i * 128;
    const int s0    = stile * 128;
    const int tid = threadIdx.x;
    const int wid = tid >> 6;
    const int lane = tid & 63;
    const int lr  = lane & 15;
    const int lk  = (lane >> 4) * 8;
    const int strow = tid >> 3;
    const int skc   = (tid & 7) * 8;

    // acc init from hpart (e-segment contribution for this s-tile)
    f32x4 acc[2][8];
    {
        const unsigned short* hp = hpart
            + ((size_t)((b * 4 + h0i) * 4 + stile)) * 16384;
#pragma unroll
        for (int st = 0; st < 2; ++st)
#pragma unroll
            for (int ht = 0; ht < 8; ++ht) {
                const int f = (wid * 2 + st) * 8 + ht;
                const uint2 uu = *(const uint2*)(hp + f * 256 + lane * 4);
                f32x4 v;
                v[0] = __uint_as_float(uu.x << 16);
                v[1] = __uint_as_float(uu.x & 0xffff0000u);
                v[2] = __uint_as_float(uu.y << 16);
                v[3] = __uint_as_float(uu.y & 0xffff0000u);
                acc[st][ht] = v;
            }
    }

    auto stage = [&](int kstep, int buf) {
        const int k0 = kstep * KSTEP;
        const unsigned short* asrc;
        int koff, bcol;
        if (k0 < DD) { asrc = leftb;  koff = k0;      bcol = k0; }
        else         { asrc = rightb; koff = k0 - DD; bcol = k0 + 256; }
#pragma unroll
        for (int j = 0; j < 4; ++j) {
            const int row = strow + 32 * j;
            const int ss = s0 + row;
            *(bf16x8*)&Abuf[buf][row][skc] =
                *(const bf16x8*)(asrc + ((size_t)ss * BB + b) * DD + koff + skc);
            *(bf16x8*)&Bbuf[buf][row][skc] =
                *(const bf16x8*)(convwb + (size_t)(h0 + row) * K3D + bcol + skc);
        }
    };

    stage(0, 0);
    int cur = 0;
    for (int it = 0; it < NKC; ++it) {
        __syncthreads();
        if (it + 1 < NKC) stage(it + 1, cur ^ 1);

        const int wrow0 = wid * 32;
#pragma unroll
        for (int ks = 0; ks < 2; ++ks) {
            const int kk = ks * 32 + lk;
            const bf16x8 a0 = *(const bf16x8*)&Abuf[cur][wrow0 + lr][kk];
            const bf16x8 a1 = *(const bf16x8*)&Abuf[cur][wrow0 + 16 + lr][kk];
#pragma unroll
            for (int ht = 0; ht < 8; ++ht) {
                const bf16x8 bv = *(const bf16x8*)&Bbuf[cur][ht * 16 + lr][kk];
                acc[0][ht] = __builtin_amdgcn_mfma_f32_16x16x32_bf16(a0, bv, acc[0][ht], 0, 0, 0);
                acc[1][ht] = __builtin_amdgcn_mfma_f32_16x16x32_bf16(a1, bv, acc[1][ht], 0, 0, 0);
            }
        }
        cur ^= 1;
    }

    // partial max over this s-tile
    float pmax[8];
#pragma unroll
    for (int ht = 0; ht < 8; ++ht) {
        float m = -INFINITY;
#pragma unroll
        for (int st = 0; st < 2; ++st)
#pragma unroll
            for (int r = 0; r < 4; ++r)
                m = fmaxf(m, acc[st][ht][r]);
        m = fmaxf(m, __shfl_xor(m, 16));
        m = fmaxf(m, __shfl_xor(m, 32));
        if (lane < 16) red[wid][ht * 16 + lane] = m;
    }
    __syncthreads();
    if (tid < 128) {
        const float m = fmaxf(fmaxf(red[0][tid], red[1][tid]),
                              fmaxf(red[2][tid], red[3][tid]));
        const float v = fmaxf(m + conv_b[h0 + tid], 0.f);
        atomicMax((unsigned*)(pooled + (size_t)b * HH + h0 + tid),
                  __float_as_uint(v));
    }
}

// ---------------------------------------------------------------------------
// Kernel 4: final FC.
// ---------------------------------------------------------------------------
__global__ void fc_kernel(const float* __restrict__ pooled,
                          const float* __restrict__ fc_w,
                          const float* __restrict__ fc_b,
                          float* __restrict__ out)
{
    const int t = threadIdx.x;
    if (t >= BB * NCLS) return;
    const int b = t / NCLS, c = t % NCLS;
    float acc = fc_b[c];
    for (int h = 0; h < HH; ++h)
        acc += pooled[(size_t)b * HH + h] * fc_w[(size_t)c * HH + h];
    out[b * NCLS + c] = acc;
}

// ---------------------------------------------------------------------------
extern "C" void kernel_launch(void* const* d_in, const int* in_sizes, int n_in,
                              void* d_out, int out_size, void* d_ws, size_t ws_size,
                              hipStream_t stream)
{
    const int*   x       = (const int*)  d_in[0];
    const float* embed_w = (const float*)d_in[1];
    const float* Wl      = (const float*)d_in[2];
    const float* bl      = (const float*)d_in[3];
    const float* Wsl     = (const float*)d_in[4];
    const float* bsl     = (const float*)d_in[5];
    const float* Wr      = (const float*)d_in[6];
    const float* br      = (const float*)d_in[7];
    const float* Wsr     = (const float*)d_in[8];
    const float* bsr     = (const float*)d_in[9];
    const float* conv_w  = (const float*)d_in[10];
    const float* conv_b  = (const float*)d_in[11];
    const float* fc_w    = (const float*)d_in[12];
    const float* fc_b    = (const float*)d_in[13];
    const float* cl0     = (const float*)d_in[14];
    const float* cr0     = (const float*)d_in[15];
    float* out = (float*)d_out;

    char* ws = (char*)d_ws;
    const size_t SZf = (size_t)SS * BB * DD * sizeof(float);           // 33.55 MB
    const size_t SZh = (size_t)SS * BB * DD * sizeof(unsigned short);  // 16.78 MB
    float*          pre2_l = (float*)(ws);
    float*          pre2_r = (float*)(ws + SZf);
    unsigned short* leftb  = (unsigned short*)(ws + 2 * SZf);
    unsigned short* rightb = (unsigned short*)(ws + 2 * SZf + SZh);
    unsigned short* e2     = (unsigned short*)(ws + 2 * SZf + 2 * SZh);
    unsigned short* convwb = (unsigned short*)(ws + 2 * SZf + 3 * SZh);
    float*          pooled = (float*)(ws + 2 * SZf + 3 * SZh + (size_t)HH * K3D * 2);
    unsigned short* hpart  = (unsigned short*)(ws + 2 * SZf + 3 * SZh
                                               + (size_t)HH * K3D * 2
                                               + (size_t)BB * HH * 4);

    hipMemsetAsync(pooled, 0, (size_t)BB * HH * sizeof(float), stream);

    prep_pre_kernel<<<5312, 256, 0, stream>>>(
        Wsl, Wsr, bsl, bl, bsr, br, x, embed_w, conv_w,
        convwb, e2, pre2_l, pre2_r);

    recur_conve_kernel<<<136, 256, 0, stream>>>(
        Wl, Wr, cl0, cr0, pre2_l, pre2_r, leftb, rightb, e2, convwb, hpart);

    conv_pool_kernel<<<1024, 256, 0, stream>>>(
        leftb, rightb, convwb, hpart, conv_b, pooled);

    fc_kernel<<<1, BB * NCLS, 0, stream>>>(pooled, fc_w, fc_b, out);
}

// Round 13
// 428.985 us; speedup vs baseline: 1.8999x; 1.0203x over previous
//
#include <hip/hip_runtime.h>
#include <hip/hip_bf16.h>

#define VOCAB 50000
#define DD 256
#define NCLS 10
#define BB 64
#define SS 512
#define HH 512
#define K3D 768

typedef __attribute__((ext_vector_type(8))) short bf16x8;
typedef __attribute__((ext_vector_type(8))) unsigned short ush8;
typedef __attribute__((ext_vector_type(4))) float f32x4;

static __device__ __forceinline__ unsigned short f2bf(float f) {
    __hip_bfloat16 h = __float2bfloat16(f);
    return *reinterpret_cast<unsigned short*>(&h);
}

static __device__ __forceinline__ ush8 cvt8(const float* src) {
    const float4 lo = *(const float4*)(src);
    const float4 hi = *(const float4*)(src + 4);
    ush8 o;
    o[0]=f2bf(lo.x); o[1]=f2bf(lo.y); o[2]=f2bf(lo.z); o[3]=f2bf(lo.w);
    o[4]=f2bf(hi.x); o[5]=f2bf(hi.y); o[6]=f2bf(hi.z); o[7]=f2bf(hi.w);
    return o;
}

// ---------------------------------------------------------------------------
// Kernel 1: prep + pre-GEMM merged (e2 materialization ELIMINATED — conv_e
// now gathers embed directly in recur's shadow).
//   bid < 1024 : pre-GEMM MFMA, staging from fp32 Wsl/Wsr + embed_w gather.
//   else       : conv_w -> bf16 (convwb), 192 blocks.
// ---------------------------------------------------------------------------
#define PPAD 72

__global__ __launch_bounds__(256) void prep_pre_kernel(
    const float* __restrict__ Wsl, const float* __restrict__ Wsr,
    const float* __restrict__ bsl, const float* __restrict__ bl,
    const float* __restrict__ bsr, const float* __restrict__ br,
    const int* __restrict__ x, const float* __restrict__ embed_w,
    const float* __restrict__ conv_w,
    unsigned short* __restrict__ convwb,
    float* __restrict__ pre2_l, float* __restrict__ pre2_r)
{
    __shared__ unsigned short Abuf[2][128][PPAD];
    __shared__ unsigned short Bbuf[2][128][PPAD];
    __shared__ int xs[128];

    const int bid = blockIdx.x;
    const int tid = threadIdx.x;

    if (bid < 1024) {
        // ---------------- pre-GEMM path ----------------
        const int mi  = bid & 3;
        const int sbi = bid >> 2;
        const int w = tid >> 6, lane = tid & 63;
        const int lr = lane & 15, g = lane >> 4;
        const int lk = g * 8;
        const int strow = tid >> 3;
        const int skc   = (tid & 7) * 8;

        if (tid < 128)
            xs[tid] = x[(tid & 63) * SS + 2 * sbi + (tid >> 6)];

        f32x4 acc[2][8];
#pragma unroll
        for (int mt = 0; mt < 2; ++mt)
#pragma unroll
            for (int nt = 0; nt < 8; ++nt) acc[mt][nt] = (f32x4)(0.f);

        auto stage = [&](int ks, int buf) {
            const int k0 = ks * 64;
#pragma unroll
            for (int j = 0; j < 4; ++j) {
                const int row = strow + 32 * j;
                const float* wsrc = (mi < 2 ? Wsl + (size_t)(mi * 128 + row) * DD
                                            : Wsr + (size_t)((mi - 2) * 128 + row) * DD)
                                    + k0 + skc;
                *(ush8*)&Abuf[buf][row][skc] = cvt8(wsrc);
                const float* esrc = embed_w + (size_t)xs[row] * DD + k0 + skc;
                *(ush8*)&Bbuf[buf][row][skc] = cvt8(esrc);
            }
        };

        __syncthreads();   // xs visible
        stage(0, 0);
        int cur = 0;
        for (int ks = 0; ks < 4; ++ks) {
            __syncthreads();
            if (ks + 1 < 4) stage(ks + 1, cur ^ 1);
#pragma unroll
            for (int k2 = 0; k2 < 2; ++k2) {
                const int kk = k2 * 32 + lk;
                const bf16x8 a0 = *(const bf16x8*)&Abuf[cur][w * 32 + lr][kk];
                const bf16x8 a1 = *(const bf16x8*)&Abuf[cur][w * 32 + 16 + lr][kk];
#pragma unroll
                for (int nt = 0; nt < 8; ++nt) {
                    const bf16x8 bv = *(const bf16x8*)&Bbuf[cur][nt * 16 + lr][kk];
                    acc[0][nt] = __builtin_amdgcn_mfma_f32_16x16x32_bf16(a0, bv, acc[0][nt], 0, 0, 0);
                    acc[1][nt] = __builtin_amdgcn_mfma_f32_16x16x32_bf16(a1, bv, acc[1][nt], 0, 0, 0);
                }
            }
            cur ^= 1;
        }

#pragma unroll
        for (int mt = 0; mt < 2; ++mt) {
            const int eg = mi * 128 + w * 32 + mt * 16 + g * 4;
            const int e  = eg & 255;
            const float* bsx = (eg < 256) ? bsl : bsr;
            const float* bbx = (eg < 256) ? bl  : br;
            const float4 b1 = *(const float4*)(bsx + e);
            const float4 b2 = *(const float4*)(bbx + e);
            float* dstb = (eg >= 256) ? pre2_r : pre2_l;
#pragma unroll
            for (int nt = 0; nt < 8; ++nt) {
                const int sb = sbi * 128 + nt * 16 + lr;
                const int s = sb >> 6, bgq = (sb >> 4) & 3, b_loc = sb & 15;
                float4 v;
                v.x = acc[mt][nt][0] + b1.x + b2.x;
                v.y = acc[mt][nt][1] + b1.y + b2.y;
                v.z = acc[mt][nt][2] + b1.z + b2.z;
                v.w = acc[mt][nt][3] + b1.w + b2.w;
                *(float4*)(dstb + ((size_t)s * 4 + bgq) * 4096 + (e >> 2) * 64 + b_loc * 4) = v;
            }
        }
    } else {
        // ---------------- conv_w -> bf16 ----------------
        const int g = (bid - 1024) * 256 + tid;
        *(ush8*)(convwb + (size_t)g * 8) = cvt8(conv_w + (size_t)g * 8);
    }
}

// ---------------------------------------------------------------------------
// Kernel 2: FUSED recur (blocks 0..7, frozen R10 structure) + conv_e
// (blocks 8..135): h_e partials = gather(embed) @ conv_w[:,256:512]^T
// -> hpart (bf16). conv_e gathers DIRECTLY from embed_w (fp32, xsv table) —
// the extra bytes run in recur's shadow, e2 materialization eliminated.
// ---------------------------------------------------------------------------
#define CSWZ(row, off) ((off) ^ (((row) & 15) << 4))
#define APAD 72

__global__ __launch_bounds__(256, 1) void recur_conve_kernel(
    const float* __restrict__ Wl, const float* __restrict__ Wr,
    const float* __restrict__ cl0, const float* __restrict__ cr0,
    const float* __restrict__ pre2_l, const float* __restrict__ pre2_r,
    unsigned short* __restrict__ outl, unsigned short* __restrict__ outr,
    const int* __restrict__ x, const float* __restrict__ embed_w,
    const unsigned short* __restrict__ convwb,
    unsigned short* __restrict__ hpart)
{
    __shared__ alignas(16) unsigned char smem[2 * 2 * 128 * APAD * 2];  // 73728B
    __shared__ int xsv[512];

    const int tid  = threadIdx.x;
    const int lane = tid & 63;

    if (blockIdx.x < 8) {
        // ================= recur path (frozen) ==========
        unsigned short* cbf0 = (unsigned short*)smem;          // [16*256]
        unsigned short* cbf1 = (unsigned short*)smem + 16 * 256;

        const int dir = blockIdx.x >> 2;
        const int bg  = blockIdx.x & 3;
        const int b0  = bg * 16;
        const int wl  = tid >> 6;
        const int col = lane & 15;
        const int g   = lane >> 4;

        const float* W   = dir ? Wr : Wl;
        const float* c0  = dir ? cr0 : cl0;
        const float* pre = dir ? pre2_r : pre2_l;
        unsigned short* out = dir ? outr : outl;

        bf16x8 wfrag[4][8];
#pragma unroll
        for (int mt = 0; mt < 4; ++mt)
#pragma unroll
            for (int i = 0; i < 8; ++i) {
                const int kt = (i + 2 * wl) & 7;
                const float* src = W + (size_t)(wl * 64 + mt * 16 + col) * DD
                                     + kt * 32 + g * 8;
                const ush8 p = cvt8(src);
                wfrag[mt][i] = *(bf16x8*)&p;
            }

        int soff[8];
#pragma unroll
        for (int i = 0; i < 8; ++i) {
            const int kt = (i + 2 * wl) & 7;
            soff[i] = CSWZ(col, kt * 64 + g * 16);
        }

        {
            const int blc = tid >> 4;
            const int ch  = tid & 15;
            const float* src = c0 + (size_t)(b0 + blc) * DD + ch * 16;
            const ush8 p0 = cvt8(src);
            const ush8 p1 = cvt8(src + 8);
            char* rowp = (char*)cbf0 + blc * 512;
            *(ush8*)(rowp + CSWZ(blc, ch * 32))      = p0;
            *(ush8*)(rowp + CSWZ(blc, ch * 32 + 16)) = p1;
            const int t0 = dir ? 511 : 0;
            ush8* dst = (ush8*)(out + ((size_t)t0 * BB + b0 + blc) * DD + ch * 16);
            dst[0] = p0; dst[1] = p1;
        }

        const int lpre = (wl * 16 + g) * 64 + col * 4;
        const ptrdiff_t pstep = dir ? -(ptrdiff_t)16384 : (ptrdiff_t)16384;
        const float* p0 = pre + ((size_t)(dir ? 511 : 0) * 4 + bg) * 4096 + lpre;

        float4 pA0 = *(const float4*)(p0);
        float4 pA1 = *(const float4*)(p0 + 256);
        float4 pA2 = *(const float4*)(p0 + 512);
        float4 pA3 = *(const float4*)(p0 + 768);
        const float* p1p = p0 + pstep;
        float4 pB0 = *(const float4*)(p1p);
        float4 pB1 = *(const float4*)(p1p + 256);
        float4 pB2 = *(const float4*)(p1p + 512);
        float4 pB3 = *(const float4*)(p1p + 768);
        const float* pfetch = p0 + 2 * pstep;

        unsigned short* oplane = out + (size_t)(dir ? 510 : 1) * BB * DD
                                     + (b0 + col) * DD + wl * 64 + g * 4;
        const ptrdiff_t ostep = (dir ? -(ptrdiff_t)1 : (ptrdiff_t)1) * (BB * DD);

        __syncthreads();

        int cur = 0;
#pragma unroll 2
        for (int k = 0; k < SS - 1; ++k) {
            bf16x8 sfrag[8];
            {
                const char* rowp = (const char*)(cur ? cbf1 : cbf0) + col * 512;
#pragma unroll
                for (int i = 0; i < 8; ++i)
                    sfrag[i] = *(const bf16x8*)(rowp + soff[i]);
            }

            const float4 pN0 = *(const float4*)(pfetch);
            const float4 pN1 = *(const float4*)(pfetch + 256);
            const float4 pN2 = *(const float4*)(pfetch + 512);
            const float4 pN3 = *(const float4*)(pfetch + 768);
            if (k < SS - 4) pfetch += pstep;

            char* nbuf = (char*)(cur ? cbf0 : cbf1) + col * 512;

            auto epi = [&](int mt, const f32x4 a) {
                const float v0 = fmaxf(a[0], 0.f);
                const float v1 = fmaxf(a[1], 0.f);
                const float v2 = fmaxf(a[2], 0.f);
                const float v3 = fmaxf(a[3], 0.f);
                uint2 uu;
                asm("v_cvt_pk_bf16_f32 %0, %1, %2" : "=v"(uu.x) : "v"(v0), "v"(v1));
                asm("v_cvt_pk_bf16_f32 %0, %1, %2" : "=v"(uu.y) : "v"(v2), "v"(v3));
                const int eoff = (wl * 64 + mt * 16 + g * 4) * 2;
                *(uint2*)(nbuf + CSWZ(col, eoff)) = uu;
                *(uint2*)(oplane + mt * 16) = uu;
            };

            f32x4 a0 = *(const f32x4*)&pA0;
            f32x4 a1 = *(const f32x4*)&pA1;
            __builtin_amdgcn_s_setprio(1);
#pragma unroll
            for (int i = 0; i < 8; ++i) {
                a0 = __builtin_amdgcn_mfma_f32_16x16x32_bf16(wfrag[0][i], sfrag[i], a0, 0, 0, 0);
                a1 = __builtin_amdgcn_mfma_f32_16x16x32_bf16(wfrag[1][i], sfrag[i], a1, 0, 0, 0);
            }
            __builtin_amdgcn_s_setprio(0);
            epi(0, a0);
            epi(1, a1);

            f32x4 a2 = *(const f32x4*)&pA2;
            f32x4 a3 = *(const f32x4*)&pA3;
            __builtin_amdgcn_s_setprio(1);
#pragma unroll
            for (int i = 0; i < 8; ++i) {
                a2 = __builtin_amdgcn_mfma_f32_16x16x32_bf16(wfrag[2][i], sfrag[i], a2, 0, 0, 0);
                a3 = __builtin_amdgcn_mfma_f32_16x16x32_bf16(wfrag[3][i], sfrag[i], a3, 0, 0, 0);
            }
            __builtin_amdgcn_s_setprio(0);
            epi(2, a2);
            epi(3, a3);

            pA0 = pB0; pA1 = pB1; pA2 = pB2; pA3 = pB3;
            pB0 = pN0; pB1 = pN1; pB2 = pN2; pB3 = pN3;
            oplane += ostep;

            asm volatile("s_waitcnt lgkmcnt(0)" ::: "memory");
            __builtin_amdgcn_s_barrier();
            asm volatile("" ::: "memory");
            cur ^= 1;
        }
        return;
    }

    // ===================== conv_e path (blocks 8..135) =====================
    unsigned short* Ab = (unsigned short*)smem;                    // [2][128][APAD]
    unsigned short* Bb = (unsigned short*)smem + 2 * 128 * APAD;

    const int wid = tid >> 6;
    const int lr  = lane & 15;
    const int lk  = (lane >> 4) * 8;
    const int strow = tid >> 3;
    const int skc   = (tid & 7) * 8;

    for (int rep = 0; rep < 2; ++rep) {
        const int cid = (blockIdx.x - 8) + rep * 128;
        const int b   = cid >> 2;
        const int h0  = (cid & 3) * 128;

        // per-batch gather table
        for (int i = tid; i < SS; i += 256) xsv[i] = x[b * SS + i];
        __syncthreads();

        f32x4 acc[2][8];
#pragma unroll
        for (int st = 0; st < 2; ++st)
#pragma unroll
            for (int ht = 0; ht < 8; ++ht) acc[st][ht] = (f32x4)(0.f);

        auto stage = [&](int it, int buf) {
            const int stile = it >> 2, kstep = it & 3;
            const int k0 = kstep * 64;
            const int s0 = stile * 128;
#pragma unroll
            for (int j = 0; j < 4; ++j) {
                const int row = strow + 32 * j;
                const int ss = s0 + row;
                const float* esrc = embed_w + (size_t)xsv[ss] * DD + k0 + skc;
                *(ush8*)&Ab[(buf * 128 + row) * APAD + skc] = cvt8(esrc);
                *(bf16x8*)&Bb[(buf * 128 + row) * APAD + skc] =
                    *(const bf16x8*)(convwb + (size_t)(h0 + row) * K3D + 256 + k0 + skc);
            }
        };

        stage(0, 0);
        int cur = 0;
        for (int it = 0; it < 16; ++it) {
            __syncthreads();
            if (it + 1 < 16) stage(it + 1, cur ^ 1);

            const int wrow0 = wid * 32;
#pragma unroll
            for (int ks = 0; ks < 2; ++ks) {
                const int kk = ks * 32 + lk;
                const bf16x8 a0 = *(const bf16x8*)&Ab[(cur * 128 + wrow0 + lr) * APAD + kk];
                const bf16x8 a1 = *(const bf16x8*)&Ab[(cur * 128 + wrow0 + 16 + lr) * APAD + kk];
#pragma unroll
                for (int ht = 0; ht < 8; ++ht) {
                    const bf16x8 bv = *(const bf16x8*)&Bb[(cur * 128 + ht * 16 + lr) * APAD + kk];
                    acc[0][ht] = __builtin_amdgcn_mfma_f32_16x16x32_bf16(a0, bv, acc[0][ht], 0, 0, 0);
                    acc[1][ht] = __builtin_amdgcn_mfma_f32_16x16x32_bf16(a1, bv, acc[1][ht], 0, 0, 0);
                }
            }
            if ((it & 3) == 3) {
                const int stile = it >> 2;
                unsigned short* hp = hpart + (size_t)(cid * 4 + stile) * 16384;
#pragma unroll
                for (int st = 0; st < 2; ++st)
#pragma unroll
                    for (int ht = 0; ht < 8; ++ht) {
                        uint2 uu;
                        asm("v_cvt_pk_bf16_f32 %0, %1, %2"
                            : "=v"(uu.x) : "v"(acc[st][ht][0]), "v"(acc[st][ht][1]));
                        asm("v_cvt_pk_bf16_f32 %0, %1, %2"
                            : "=v"(uu.y) : "v"(acc[st][ht][2]), "v"(acc[st][ht][3]));
                        const int f = (wid * 2 + st) * 8 + ht;
                        *(uint2*)(hp + f * 256 + lane * 4) = uu;
                        acc[st][ht] = (f32x4)(0.f);
                    }
            }
            cur ^= 1;
        }
        __syncthreads();
    }
}

// ---------------------------------------------------------------------------
// Kernel 3: conv(left|right) + hpart(e) + relu + maxpool.
// grid = 1024 (b, h0, stile); per-block partial max -> pooled via atomicMax
// on the fp32 bit-pattern (all values >= 0 post-relu => valid).
// ---------------------------------------------------------------------------
#define KSTEP 64
#define NKC 8

__global__ __launch_bounds__(256) void conv_pool_kernel(
    const unsigned short* __restrict__ leftb,
    const unsigned short* __restrict__ rightb,
    const unsigned short* __restrict__ convwb,
    const unsigned short* __restrict__ hpart,
    const float* __restrict__ conv_b,
    float* __restrict__ pooled)
{
    __shared__ unsigned short Abuf[2][128][APAD];
    __shared__ unsigned short Bbuf[2][128][APAD];
    __shared__ float red[4][128];

    const int stile = blockIdx.x & 3;
    const int h0i   = (blockIdx.x >> 2) & 3;
    const int b     = blockIdx.x >> 4;
    const int h0    = h0i * 128;
    const int s0    = stile * 128;
    const int tid = threadIdx.x;
    const int wid = tid >> 6;
    const int lane = tid & 63;
    const int lr  = lane & 15;
    const int lk  = (lane >> 4) * 8;
    const int strow = tid >> 3;
    const int skc   = (tid & 7) * 8;

    f32x4 acc[2][8];
    {
        const unsigned short* hp = hpart
            + ((size_t)((b * 4 + h0i) * 4 + stile)) * 16384;
#pragma unroll
        for (int st = 0; st < 2; ++st)
#pragma unroll
            for (int ht = 0; ht < 8; ++ht) {
                const int f = (wid * 2 + st) * 8 + ht;
                const uint2 uu = *(const uint2*)(hp + f * 256 + lane * 4);
                f32x4 v;
                v[0] = __uint_as_float(uu.x << 16);
                v[1] = __uint_as_float(uu.x & 0xffff0000u);
                v[2] = __uint_as_float(uu.y << 16);
                v[3] = __uint_as_float(uu.y & 0xffff0000u);
                acc[st][ht] = v;
            }
    }

    auto stage = [&](int kstep, int buf) {
        const int k0 = kstep * KSTEP;
        const unsigned short* asrc;
        int koff, bcol;
        if (k0 < DD) { asrc = leftb;  koff = k0;      bcol = k0; }
        else         { asrc = rightb; koff = k0 - DD; bcol = k0 + 256; }
#pragma unroll
        for (int j = 0; j < 4; ++j) {
            const int row = strow + 32 * j;
            const int ss = s0 + row;
            *(bf16x8*)&Abuf[buf][row][skc] =
                *(const bf16x8*)(asrc + ((size_t)ss * BB + b) * DD + koff + skc);
            *(bf16x8*)&Bbuf[buf][row][skc] =
                *(const bf16x8*)(convwb + (size_t)(h0 + row) * K3D + bcol + skc);
        }
    };

    stage(0, 0);
    int cur = 0;
    for (int it = 0; it < NKC; ++it) {
        __syncthreads();
        if (it + 1 < NKC) stage(it + 1, cur ^ 1);

        const int wrow0 = wid * 32;
#pragma unroll
        for (int ks = 0; ks < 2; ++ks) {
            const int kk = ks * 32 + lk;
            const bf16x8 a0 = *(const bf16x8*)&Abuf[cur][wrow0 + lr][kk];
            const bf16x8 a1 = *(const bf16x8*)&Abuf[cur][wrow0 + 16 + lr][kk];
#pragma unroll
            for (int ht = 0; ht < 8; ++ht) {
                const bf16x8 bv = *(const bf16x8*)&Bbuf[cur][ht * 16 + lr][kk];
                acc[0][ht] = __builtin_amdgcn_mfma_f32_16x16x32_bf16(a0, bv, acc[0][ht], 0, 0, 0);
                acc[1][ht] = __builtin_amdgcn_mfma_f32_16x16x32_bf16(a1, bv, acc[1][ht], 0, 0, 0);
            }
        }
        cur ^= 1;
    }

    float pmax[8];
#pragma unroll
    for (int ht = 0; ht < 8; ++ht) {
        float m = -INFINITY;
#pragma unroll
        for (int st = 0; st < 2; ++st)
#pragma unroll
            for (int r = 0; r < 4; ++r)
                m = fmaxf(m, acc[st][ht][r]);
        m = fmaxf(m, __shfl_xor(m, 16));
        m = fmaxf(m, __shfl_xor(m, 32));
        if (lane < 16) red[wid][ht * 16 + lane] = m;
    }
    __syncthreads();
    if (tid < 128) {
        const float m = fmaxf(fmaxf(red[0][tid], red[1][tid]),
                              fmaxf(red[2][tid], red[3][tid]));
        const float v = fmaxf(m + conv_b[h0 + tid], 0.f);
        atomicMax((unsigned*)(pooled + (size_t)b * HH + h0 + tid),
                  __float_as_uint(v));
    }
}

// ---------------------------------------------------------------------------
// Kernel 4: final FC.
// ---------------------------------------------------------------------------
__global__ void fc_kernel(const float* __restrict__ pooled,
                          const float* __restrict__ fc_w,
                          const float* __restrict__ fc_b,
                          float* __restrict__ out)
{
    const int t = threadIdx.x;
    if (t >= BB * NCLS) return;
    const int b = t / NCLS, c = t % NCLS;
    float acc = fc_b[c];
    for (int h = 0; h < HH; ++h)
        acc += pooled[(size_t)b * HH + h] * fc_w[(size_t)c * HH + h];
    out[b * NCLS + c] = acc;
}

// ---------------------------------------------------------------------------
extern "C" void kernel_launch(void* const* d_in, const int* in_sizes, int n_in,
                              void* d_out, int out_size, void* d_ws, size_t ws_size,
                              hipStream_t stream)
{
    const int*   x       = (const int*)  d_in[0];
    const float* embed_w = (const float*)d_in[1];
    const float* Wl      = (const float*)d_in[2];
    const float* bl      = (const float*)d_in[3];
    const float* Wsl     = (const float*)d_in[4];
    const float* bsl     = (const float*)d_in[5];
    const float* Wr      = (const float*)d_in[6];
    const float* br      = (const float*)d_in[7];
    const float* Wsr     = (const float*)d_in[8];
    const float* bsr     = (const float*)d_in[9];
    const float* conv_w  = (const float*)d_in[10];
    const float* conv_b  = (const float*)d_in[11];
    const float* fc_w    = (const float*)d_in[12];
    const float* fc_b    = (const float*)d_in[13];
    const float* cl0     = (const float*)d_in[14];
    const float* cr0     = (const float*)d_in[15];
    float* out = (float*)d_out;

    char* ws = (char*)d_ws;
    const size_t SZf = (size_t)SS * BB * DD * sizeof(float);           // 33.55 MB
    const size_t SZh = (size_t)SS * BB * DD * sizeof(unsigned short);  // 16.78 MB
    float*          pre2_l = (float*)(ws);
    float*          pre2_r = (float*)(ws + SZf);
    unsigned short* leftb  = (unsigned short*)(ws + 2 * SZf);
    unsigned short* rightb = (unsigned short*)(ws + 2 * SZf + SZh);
    unsigned short* convwb = (unsigned short*)(ws + 2 * SZf + 2 * SZh);
    float*          pooled = (float*)(ws + 2 * SZf + 2 * SZh + (size_t)HH * K3D * 2);
    unsigned short* hpart  = (unsigned short*)(ws + 2 * SZf + 2 * SZh
                                               + (size_t)HH * K3D * 2
                                               + (size_t)BB * HH * 4);

    hipMemsetAsync(pooled, 0, (size_t)BB * HH * sizeof(float), stream);

    prep_pre_kernel<<<1216, 256, 0, stream>>>(
        Wsl, Wsr, bsl, bl, bsr, br, x, embed_w, conv_w,
        convwb, pre2_l, pre2_r);

    recur_conve_kernel<<<136, 256, 0, stream>>>(
        Wl, Wr, cl0, cr0, pre2_l, pre2_r, leftb, rightb,
        x, embed_w, convwb, hpart);

    conv_pool_kernel<<<1024, 256, 0, stream>>>(
        leftb, rightb, convwb, hpart, conv_b, pooled);

    fc_kernel<<<1, BB * NCLS, 0, stream>>>(pooled, fc_w, fc_b, out);
}

// Round 14
// 425.956 us; speedup vs baseline: 1.9135x; 1.0071x over previous
//
#include <hip/hip_runtime.h>
#include <hip/hip_bf16.h>

#define VOCAB 50000
#define DD 256
#define NCLS 10
#define BB 64
#define SS 512
#define HH 512
#define K3D 768

typedef __attribute__((ext_vector_type(8))) short bf16x8;
typedef __attribute__((ext_vector_type(8))) unsigned short ush8;
typedef __attribute__((ext_vector_type(4))) float f32x4;

static __device__ __forceinline__ unsigned short f2bf(float f) {
    __hip_bfloat16 h = __float2bfloat16(f);
    return *reinterpret_cast<unsigned short*>(&h);
}

// 8x fp32 -> 8x bf16 via v_cvt_pk_bf16_f32 (4 instrs instead of ~32).
// Packing: low half <- src0, high <- src1 (same as the R10 epilogue; RNE).
static __device__ __forceinline__ ush8 cvt8(const float* src) {
    const float4 lo = *(const float4*)(src);
    const float4 hi = *(const float4*)(src + 4);
    uint4 u;
    asm("v_cvt_pk_bf16_f32 %0, %1, %2" : "=v"(u.x) : "v"(lo.x), "v"(lo.y));
    asm("v_cvt_pk_bf16_f32 %0, %1, %2" : "=v"(u.y) : "v"(lo.z), "v"(lo.w));
    asm("v_cvt_pk_bf16_f32 %0, %1, %2" : "=v"(u.z) : "v"(hi.x), "v"(hi.y));
    asm("v_cvt_pk_bf16_f32 %0, %1, %2" : "=v"(u.w) : "v"(hi.z), "v"(hi.w));
    return *reinterpret_cast<ush8*>(&u);
}

// ---------------------------------------------------------------------------
// Kernel 1: prep + pre-GEMM merged.
//   bid < 1024 : pre-GEMM MFMA (fp32 Wsl/Wsr + embed gather, cvt_pk staging)
//   bid < 1216 : conv_w -> bf16 (convwb)
//   bid == 1216: pooled zero-init (replaces hipMemsetAsync)
// ---------------------------------------------------------------------------
#define PPAD 72

__global__ __launch_bounds__(256) void prep_pre_kernel(
    const float* __restrict__ Wsl, const float* __restrict__ Wsr,
    const float* __restrict__ bsl, const float* __restrict__ bl,
    const float* __restrict__ bsr, const float* __restrict__ br,
    const int* __restrict__ x, const float* __restrict__ embed_w,
    const float* __restrict__ conv_w,
    unsigned short* __restrict__ convwb,
    float* __restrict__ pre2_l, float* __restrict__ pre2_r,
    float* __restrict__ pooled)
{
    __shared__ unsigned short Abuf[2][128][PPAD];
    __shared__ unsigned short Bbuf[2][128][PPAD];
    __shared__ int xs[128];

    const int bid = blockIdx.x;
    const int tid = threadIdx.x;

    if (bid < 1024) {
        // ---------------- pre-GEMM path ----------------
        const int mi  = bid & 3;
        const int sbi = bid >> 2;
        const int w = tid >> 6, lane = tid & 63;
        const int lr = lane & 15, g = lane >> 4;
        const int lk = g * 8;
        const int strow = tid >> 3;
        const int skc   = (tid & 7) * 8;

        if (tid < 128)
            xs[tid] = x[(tid & 63) * SS + 2 * sbi + (tid >> 6)];

        f32x4 acc[2][8];
#pragma unroll
        for (int mt = 0; mt < 2; ++mt)
#pragma unroll
            for (int nt = 0; nt < 8; ++nt) acc[mt][nt] = (f32x4)(0.f);

        auto stage = [&](int ks, int buf) {
            const int k0 = ks * 64;
#pragma unroll
            for (int j = 0; j < 4; ++j) {
                const int row = strow + 32 * j;
                const float* wsrc = (mi < 2 ? Wsl + (size_t)(mi * 128 + row) * DD
                                            : Wsr + (size_t)((mi - 2) * 128 + row) * DD)
                                    + k0 + skc;
                *(ush8*)&Abuf[buf][row][skc] = cvt8(wsrc);
                const float* esrc = embed_w + (size_t)xs[row] * DD + k0 + skc;
                *(ush8*)&Bbuf[buf][row][skc] = cvt8(esrc);
            }
        };

        __syncthreads();   // xs visible
        stage(0, 0);
        int cur = 0;
        for (int ks = 0; ks < 4; ++ks) {
            __syncthreads();
            if (ks + 1 < 4) stage(ks + 1, cur ^ 1);
#pragma unroll
            for (int k2 = 0; k2 < 2; ++k2) {
                const int kk = k2 * 32 + lk;
                const bf16x8 a0 = *(const bf16x8*)&Abuf[cur][w * 32 + lr][kk];
                const bf16x8 a1 = *(const bf16x8*)&Abuf[cur][w * 32 + 16 + lr][kk];
#pragma unroll
                for (int nt = 0; nt < 8; ++nt) {
                    const bf16x8 bv = *(const bf16x8*)&Bbuf[cur][nt * 16 + lr][kk];
                    acc[0][nt] = __builtin_amdgcn_mfma_f32_16x16x32_bf16(a0, bv, acc[0][nt], 0, 0, 0);
                    acc[1][nt] = __builtin_amdgcn_mfma_f32_16x16x32_bf16(a1, bv, acc[1][nt], 0, 0, 0);
                }
            }
            cur ^= 1;
        }

#pragma unroll
        for (int mt = 0; mt < 2; ++mt) {
            const int eg = mi * 128 + w * 32 + mt * 16 + g * 4;
            const int e  = eg & 255;
            const float* bsx = (eg < 256) ? bsl : bsr;
            const float* bbx = (eg < 256) ? bl  : br;
            const float4 b1 = *(const float4*)(bsx + e);
            const float4 b2 = *(const float4*)(bbx + e);
            float* dstb = (eg >= 256) ? pre2_r : pre2_l;
#pragma unroll
            for (int nt = 0; nt < 8; ++nt) {
                const int sb = sbi * 128 + nt * 16 + lr;
                const int s = sb >> 6, bgq = (sb >> 4) & 3, b_loc = sb & 15;
                float4 v;
                v.x = acc[mt][nt][0] + b1.x + b2.x;
                v.y = acc[mt][nt][1] + b1.y + b2.y;
                v.z = acc[mt][nt][2] + b1.z + b2.z;
                v.w = acc[mt][nt][3] + b1.w + b2.w;
                *(float4*)(dstb + ((size_t)s * 4 + bgq) * 4096 + (e >> 2) * 64 + b_loc * 4) = v;
            }
        }
    } else if (bid < 1216) {
        // ---------------- conv_w -> bf16 ----------------
        const int g = (bid - 1024) * 256 + tid;
        *(ush8*)(convwb + (size_t)g * 8) = cvt8(conv_w + (size_t)g * 8);
    } else {
        // ---------------- pooled zero-init ----------------
        float4* p = (float4*)pooled;
#pragma unroll
        for (int i = 0; i < 32; ++i)
            p[tid + 256 * i] = make_float4(0.f, 0.f, 0.f, 0.f);
    }
}

// ---------------------------------------------------------------------------
// Kernel 2: FUSED recur (blocks 0..7, frozen R10 structure) + conv_e
// (blocks 8..135): h_e partials = gather(embed) @ conv_w[:,256:512]^T
// -> hpart (bf16), gathered directly from embed_w in recur's shadow.
// ---------------------------------------------------------------------------
#define CSWZ(row, off) ((off) ^ (((row) & 15) << 4))
#define APAD 72

__global__ __launch_bounds__(256, 1) void recur_conve_kernel(
    const float* __restrict__ Wl, const float* __restrict__ Wr,
    const float* __restrict__ cl0, const float* __restrict__ cr0,
    const float* __restrict__ pre2_l, const float* __restrict__ pre2_r,
    unsigned short* __restrict__ outl, unsigned short* __restrict__ outr,
    const int* __restrict__ x, const float* __restrict__ embed_w,
    const unsigned short* __restrict__ convwb,
    unsigned short* __restrict__ hpart)
{
    __shared__ alignas(16) unsigned char smem[2 * 2 * 128 * APAD * 2];  // 73728B
    __shared__ int xsv[512];

    const int tid  = threadIdx.x;
    const int lane = tid & 63;

    if (blockIdx.x < 8) {
        // ================= recur path (frozen) ==========
        unsigned short* cbf0 = (unsigned short*)smem;          // [16*256]
        unsigned short* cbf1 = (unsigned short*)smem + 16 * 256;

        const int dir = blockIdx.x >> 2;
        const int bg  = blockIdx.x & 3;
        const int b0  = bg * 16;
        const int wl  = tid >> 6;
        const int col = lane & 15;
        const int g   = lane >> 4;

        const float* W   = dir ? Wr : Wl;
        const float* c0  = dir ? cr0 : cl0;
        const float* pre = dir ? pre2_r : pre2_l;
        unsigned short* out = dir ? outr : outl;

        bf16x8 wfrag[4][8];
#pragma unroll
        for (int mt = 0; mt < 4; ++mt)
#pragma unroll
            for (int i = 0; i < 8; ++i) {
                const int kt = (i + 2 * wl) & 7;
                const float* src = W + (size_t)(wl * 64 + mt * 16 + col) * DD
                                     + kt * 32 + g * 8;
                const ush8 p = cvt8(src);
                wfrag[mt][i] = *(bf16x8*)&p;
            }

        int soff[8];
#pragma unroll
        for (int i = 0; i < 8; ++i) {
            const int kt = (i + 2 * wl) & 7;
            soff[i] = CSWZ(col, kt * 64 + g * 16);
        }

        {
            const int blc = tid >> 4;
            const int ch  = tid & 15;
            const float* src = c0 + (size_t)(b0 + blc) * DD + ch * 16;
            const ush8 p0 = cvt8(src);
            const ush8 p1 = cvt8(src + 8);
            char* rowp = (char*)cbf0 + blc * 512;
            *(ush8*)(rowp + CSWZ(blc, ch * 32))      = p0;
            *(ush8*)(rowp + CSWZ(blc, ch * 32 + 16)) = p1;
            const int t0 = dir ? 511 : 0;
            ush8* dst = (ush8*)(out + ((size_t)t0 * BB + b0 + blc) * DD + ch * 16);
            dst[0] = p0; dst[1] = p1;
        }

        const int lpre = (wl * 16 + g) * 64 + col * 4;
        const ptrdiff_t pstep = dir ? -(ptrdiff_t)16384 : (ptrdiff_t)16384;
        const float* p0 = pre + ((size_t)(dir ? 511 : 0) * 4 + bg) * 4096 + lpre;

        float4 pA0 = *(const float4*)(p0);
        float4 pA1 = *(const float4*)(p0 + 256);
        float4 pA2 = *(const float4*)(p0 + 512);
        float4 pA3 = *(const float4*)(p0 + 768);
        const float* p1p = p0 + pstep;
        float4 pB0 = *(const float4*)(p1p);
        float4 pB1 = *(const float4*)(p1p + 256);
        float4 pB2 = *(const float4*)(p1p + 512);
        float4 pB3 = *(const float4*)(p1p + 768);
        const float* pfetch = p0 + 2 * pstep;

        unsigned short* oplane = out + (size_t)(dir ? 510 : 1) * BB * DD
                                     + (b0 + col) * DD + wl * 64 + g * 4;
        const ptrdiff_t ostep = (dir ? -(ptrdiff_t)1 : (ptrdiff_t)1) * (BB * DD);

        __syncthreads();

        int cur = 0;
#pragma unroll 2
        for (int k = 0; k < SS - 1; ++k) {
            bf16x8 sfrag[8];
            {
                const char* rowp = (const char*)(cur ? cbf1 : cbf0) + col * 512;
#pragma unroll
                for (int i = 0; i < 8; ++i)
                    sfrag[i] = *(const bf16x8*)(rowp + soff[i]);
            }

            const float4 pN0 = *(const float4*)(pfetch);
            const float4 pN1 = *(const float4*)(pfetch + 256);
            const float4 pN2 = *(const float4*)(pfetch + 512);
            const float4 pN3 = *(const float4*)(pfetch + 768);
            if (k < SS - 4) pfetch += pstep;

            char* nbuf = (char*)(cur ? cbf0 : cbf1) + col * 512;

            auto epi = [&](int mt, const f32x4 a) {
                const float v0 = fmaxf(a[0], 0.f);
                const float v1 = fmaxf(a[1], 0.f);
                const float v2 = fmaxf(a[2], 0.f);
                const float v3 = fmaxf(a[3], 0.f);
                uint2 uu;
                asm("v_cvt_pk_bf16_f32 %0, %1, %2" : "=v"(uu.x) : "v"(v0), "v"(v1));
                asm("v_cvt_pk_bf16_f32 %0, %1, %2" : "=v"(uu.y) : "v"(v2), "v"(v3));
                const int eoff = (wl * 64 + mt * 16 + g * 4) * 2;
                *(uint2*)(nbuf + CSWZ(col, eoff)) = uu;
                *(uint2*)(oplane + mt * 16) = uu;
            };

            f32x4 a0 = *(const f32x4*)&pA0;
            f32x4 a1 = *(const f32x4*)&pA1;
            __builtin_amdgcn_s_setprio(1);
#pragma unroll
            for (int i = 0; i < 8; ++i) {
                a0 = __builtin_amdgcn_mfma_f32_16x16x32_bf16(wfrag[0][i], sfrag[i], a0, 0, 0, 0);
                a1 = __builtin_amdgcn_mfma_f32_16x16x32_bf16(wfrag[1][i], sfrag[i], a1, 0, 0, 0);
            }
            __builtin_amdgcn_s_setprio(0);
            epi(0, a0);
            epi(1, a1);

            f32x4 a2 = *(const f32x4*)&pA2;
            f32x4 a3 = *(const f32x4*)&pA3;
            __builtin_amdgcn_s_setprio(1);
#pragma unroll
            for (int i = 0; i < 8; ++i) {
                a2 = __builtin_amdgcn_mfma_f32_16x16x32_bf16(wfrag[2][i], sfrag[i], a2, 0, 0, 0);
                a3 = __builtin_amdgcn_mfma_f32_16x16x32_bf16(wfrag[3][i], sfrag[i], a3, 0, 0, 0);
            }
            __builtin_amdgcn_s_setprio(0);
            epi(2, a2);
            epi(3, a3);

            pA0 = pB0; pA1 = pB1; pA2 = pB2; pA3 = pB3;
            pB0 = pN0; pB1 = pN1; pB2 = pN2; pB3 = pN3;
            oplane += ostep;

            asm volatile("s_waitcnt lgkmcnt(0)" ::: "memory");
            __builtin_amdgcn_s_barrier();
            asm volatile("" ::: "memory");
            cur ^= 1;
        }
        return;
    }

    // ===================== conv_e path (blocks 8..135) =====================
    unsigned short* Ab = (unsigned short*)smem;                    // [2][128][APAD]
    unsigned short* Bb = (unsigned short*)smem + 2 * 128 * APAD;

    const int wid = tid >> 6;
    const int lr  = lane & 15;
    const int lk  = (lane >> 4) * 8;
    const int strow = tid >> 3;
    const int skc   = (tid & 7) * 8;

    for (int rep = 0; rep < 2; ++rep) {
        const int cid = (blockIdx.x - 8) + rep * 128;
        const int b   = cid >> 2;
        const int h0  = (cid & 3) * 128;

        // per-batch gather table
        for (int i = tid; i < SS; i += 256) xsv[i] = x[b * SS + i];
        __syncthreads();

        f32x4 acc[2][8];
#pragma unroll
        for (int st = 0; st < 2; ++st)
#pragma unroll
            for (int ht = 0; ht < 8; ++ht) acc[st][ht] = (f32x4)(0.f);

        auto stage = [&](int it, int buf) {
            const int stile = it >> 2, kstep = it & 3;
            const int k0 = kstep * 64;
            const int s0 = stile * 128;
#pragma unroll
            for (int j = 0; j < 4; ++j) {
                const int row = strow + 32 * j;
                const int ss = s0 + row;
                const float* esrc = embed_w + (size_t)xsv[ss] * DD + k0 + skc;
                *(ush8*)&Ab[(buf * 128 + row) * APAD + skc] = cvt8(esrc);
                *(bf16x8*)&Bb[(buf * 128 + row) * APAD + skc] =
                    *(const bf16x8*)(convwb + (size_t)(h0 + row) * K3D + 256 + k0 + skc);
            }
        };

        stage(0, 0);
        int cur = 0;
        for (int it = 0; it < 16; ++it) {
            __syncthreads();
            if (it + 1 < 16) stage(it + 1, cur ^ 1);

            const int wrow0 = wid * 32;
#pragma unroll
            for (int ks = 0; ks < 2; ++ks) {
                const int kk = ks * 32 + lk;
                const bf16x8 a0 = *(const bf16x8*)&Ab[(cur * 128 + wrow0 + lr) * APAD + kk];
                const bf16x8 a1 = *(const bf16x8*)&Ab[(cur * 128 + wrow0 + 16 + lr) * APAD + kk];
#pragma unroll
                for (int ht = 0; ht < 8; ++ht) {
                    const bf16x8 bv = *(const bf16x8*)&Bb[(cur * 128 + ht * 16 + lr) * APAD + kk];
                    acc[0][ht] = __builtin_amdgcn_mfma_f32_16x16x32_bf16(a0, bv, acc[0][ht], 0, 0, 0);
                    acc[1][ht] = __builtin_amdgcn_mfma_f32_16x16x32_bf16(a1, bv, acc[1][ht], 0, 0, 0);
                }
            }
            if ((it & 3) == 3) {
                const int stile = it >> 2;
                unsigned short* hp = hpart + (size_t)(cid * 4 + stile) * 16384;
#pragma unroll
                for (int st = 0; st < 2; ++st)
#pragma unroll
                    for (int ht = 0; ht < 8; ++ht) {
                        uint2 uu;
                        asm("v_cvt_pk_bf16_f32 %0, %1, %2"
                            : "=v"(uu.x) : "v"(acc[st][ht][0]), "v"(acc[st][ht][1]));
                        asm("v_cvt_pk_bf16_f32 %0, %1, %2"
                            : "=v"(uu.y) : "v"(acc[st][ht][2]), "v"(acc[st][ht][3]));
                        const int f = (wid * 2 + st) * 8 + ht;
                        *(uint2*)(hp + f * 256 + lane * 4) = uu;
                        acc[st][ht] = (f32x4)(0.f);
                    }
            }
            cur ^= 1;
        }
        __syncthreads();
    }
}

// ---------------------------------------------------------------------------
// Kernel 3: conv(left|right) + hpart(e) + relu + maxpool.
// grid = 1024 (b, h0, stile); per-block partial max -> pooled via atomicMax
// on the fp32 bit-pattern (all values >= 0 post-relu => valid).
// ---------------------------------------------------------------------------
#define KSTEP 64
#define NKC 8

__global__ __launch_bounds__(256) void conv_pool_kernel(
    const unsigned short* __restrict__ leftb,
    const unsigned short* __restrict__ rightb,
    const unsigned short* __restrict__ convwb,
    const unsigned short* __restrict__ hpart,
    const float* __restrict__ conv_b,
    float* __restrict__ pooled)
{
    __shared__ unsigned short Abuf[2][128][APAD];
    __shared__ unsigned short Bbuf[2][128][APAD];
    __shared__ float red[4][128];

    const int stile = blockIdx.x & 3;
    const int h0i   = (blockIdx.x >> 2) & 3;
    const int b     = blockIdx.x >> 4;
    const int h0    = h0i * 128;
    const int s0    = stile * 128;
    const int tid = threadIdx.x;
    const int wid = tid >> 6;
    const int lane = tid & 63;
    const int lr  = lane & 15;
    const int lk  = (lane >> 4) * 8;
    const int strow = tid >> 3;
    const int skc   = (tid & 7) * 8;

    f32x4 acc[2][8];
    {
        const unsigned short* hp = hpart
            + ((size_t)((b * 4 + h0i) * 4 + stile)) * 16384;
#pragma unroll
        for (int st = 0; st < 2; ++st)
#pragma unroll
            for (int ht = 0; ht < 8; ++ht) {
                const int f = (wid * 2 + st) * 8 + ht;
                const uint2 uu = *(const uint2*)(hp + f * 256 + lane * 4);
                f32x4 v;
                v[0] = __uint_as_float(uu.x << 16);
                v[1] = __uint_as_float(uu.x & 0xffff0000u);
                v[2] = __uint_as_float(uu.y << 16);
                v[3] = __uint_as_float(uu.y & 0xffff0000u);
                acc[st][ht] = v;
            }
    }

    auto stage = [&](int kstep, int buf) {
        const int k0 = kstep * KSTEP;
        const unsigned short* asrc;
        int koff, bcol;
        if (k0 < DD) { asrc = leftb;  koff = k0;      bcol = k0; }
        else         { asrc = rightb; koff = k0 - DD; bcol = k0 + 256; }
#pragma unroll
        for (int j = 0; j < 4; ++j) {
            const int row = strow + 32 * j;
            const int ss = s0 + row;
            *(bf16x8*)&Abuf[buf][row][skc] =
                *(const bf16x8*)(asrc + ((size_t)ss * BB + b) * DD + koff + skc);
            *(bf16x8*)&Bbuf[buf][row][skc] =
                *(const bf16x8*)(convwb + (size_t)(h0 + row) * K3D + bcol + skc);
        }
    };

    stage(0, 0);
    int cur = 0;
    for (int it = 0; it < NKC; ++it) {
        __syncthreads();
        if (it + 1 < NKC) stage(it + 1, cur ^ 1);

        const int wrow0 = wid * 32;
#pragma unroll
        for (int ks = 0; ks < 2; ++ks) {
            const int kk = ks * 32 + lk;
            const bf16x8 a0 = *(const bf16x8*)&Abuf[cur][wrow0 + lr][kk];
            const bf16x8 a1 = *(const bf16x8*)&Abuf[cur][wrow0 + 16 + lr][kk];
#pragma unroll
            for (int ht = 0; ht < 8; ++ht) {
                const bf16x8 bv = *(const bf16x8*)&Bbuf[cur][ht * 16 + lr][kk];
                acc[0][ht] = __builtin_amdgcn_mfma_f32_16x16x32_bf16(a0, bv, acc[0][ht], 0, 0, 0);
                acc[1][ht] = __builtin_amdgcn_mfma_f32_16x16x32_bf16(a1, bv, acc[1][ht], 0, 0, 0);
            }
        }
        cur ^= 1;
    }

    float pmax[8];
#pragma unroll
    for (int ht = 0; ht < 8; ++ht) {
        float m = -INFINITY;
#pragma unroll
        for (int st = 0; st < 2; ++st)
#pragma unroll
            for (int r = 0; r < 4; ++r)
                m = fmaxf(m, acc[st][ht][r]);
        m = fmaxf(m, __shfl_xor(m, 16));
        m = fmaxf(m, __shfl_xor(m, 32));
        if (lane < 16) red[wid][ht * 16 + lane] = m;
    }
    __syncthreads();
    if (tid < 128) {
        const float m = fmaxf(fmaxf(red[0][tid], red[1][tid]),
                              fmaxf(red[2][tid], red[3][tid]));
        const float v = fmaxf(m + conv_b[h0 + tid], 0.f);
        atomicMax((unsigned*)(pooled + (size_t)b * HH + h0 + tid),
                  __float_as_uint(v));
    }
}

// ---------------------------------------------------------------------------
// Kernel 4: final FC.
// ---------------------------------------------------------------------------
__global__ void fc_kernel(const float* __restrict__ pooled,
                          const float* __restrict__ fc_w,
                          const float* __restrict__ fc_b,
                          float* __restrict__ out)
{
    const int t = threadIdx.x;
    if (t >= BB * NCLS) return;
    const int b = t / NCLS, c = t % NCLS;
    float acc = fc_b[c];
    for (int h = 0; h < HH; ++h)
        acc += pooled[(size_t)b * HH + h] * fc_w[(size_t)c * HH + h];
    out[b * NCLS + c] = acc;
}

// ---------------------------------------------------------------------------
extern "C" void kernel_launch(void* const* d_in, const int* in_sizes, int n_in,
                              void* d_out, int out_size, void* d_ws, size_t ws_size,
                              hipStream_t stream)
{
    const int*   x       = (const int*)  d_in[0];
    const float* embed_w = (const float*)d_in[1];
    const float* Wl      = (const float*)d_in[2];
    const float* bl      = (const float*)d_in[3];
    const float* Wsl     = (const float*)d_in[4];
    const float* bsl     = (const float*)d_in[5];
    const float* Wr      = (const float*)d_in[6];
    const float* br      = (const float*)d_in[7];
    const float* Wsr     = (const float*)d_in[8];
    const float* bsr     = (const float*)d_in[9];
    const float* conv_w  = (const float*)d_in[10];
    const float* conv_b  = (const float*)d_in[11];
    const float* fc_w    = (const float*)d_in[12];
    const float* fc_b    = (const float*)d_in[13];
    const float* cl0     = (const float*)d_in[14];
    const float* cr0     = (const float*)d_in[15];
    float* out = (float*)d_out;

    char* ws = (char*)d_ws;
    const size_t SZf = (size_t)SS * BB * DD * sizeof(float);           // 33.55 MB
    const size_t SZh = (size_t)SS * BB * DD * sizeof(unsigned short);  // 16.78 MB
    float*          pre2_l = (float*)(ws);
    float*          pre2_r = (float*)(ws + SZf);
    unsigned short* leftb  = (unsigned short*)(ws + 2 * SZf);
    unsigned short* rightb = (unsigned short*)(ws + 2 * SZf + SZh);
    unsigned short* convwb = (unsigned short*)(ws + 2 * SZf + 2 * SZh);
    float*          pooled = (float*)(ws + 2 * SZf + 2 * SZh + (size_t)HH * K3D * 2);
    unsigned short* hpart  = (unsigned short*)(ws + 2 * SZf + 2 * SZh
                                               + (size_t)HH * K3D * 2
                                               + (size_t)BB * HH * 4);

    prep_pre_kernel<<<1217, 256, 0, stream>>>(
        Wsl, Wsr, bsl, bl, bsr, br, x, embed_w, conv_w,
        convwb, pre2_l, pre2_r, pooled);

    recur_conve_kernel<<<136, 256, 0, stream>>>(
        Wl, Wr, cl0, cr0, pre2_l, pre2_r, leftb, rightb,
        x, embed_w, convwb, hpart);

    conv_pool_kernel<<<1024, 256, 0, stream>>>(
        leftb, rightb, convwb, hpart, conv_b, pooled);

    fc_kernel<<<1, BB * NCLS, 0, stream>>>(pooled, fc_w, fc_b, out);
}